// Round 1
// 432.442 us; speedup vs baseline: 1.0662x; 1.0662x over previous
//
#include <hip/hip_runtime.h>
#include <math.h>

// ---------------------------------------------------------------------------
// ImplicitFlowDecoder — R10:
//  - prep consolidated: constexpr per-layer swizzle (no runtime int-div) +
//    LDS-tiled coalesced feat1 transpose, single dispatch (was ~66us -> ~12us)
//  - H0 K-pad 288 -> 272 (260 rounds to 17x16): -4 MFMA/wave, -28 zero K rows
//  - gather_tile_T vectorized to uint4 (16B global loads, ds_write_b128)
//  - gelu/sigmoid: exp2 with log2e folded into constants (kills hidden v_mul)
//  - s_setprio(1) around MFMA K-loops (blocks at independent phases)
// R9 base: sigmoid-form tanh-GELU; R8: coalesced warped gather, K-unrolled
// 32x32x16 MFMA, bias-in-accumulator, in-place single-buffer LDS, 4 blocks/CU.
// ---------------------------------------------------------------------------

typedef short bf16x8 __attribute__((ext_vector_type(8)));
typedef float f32x16 __attribute__((ext_vector_type(16)));

constexpr int W8 = 64, H8 = 48, W16g = 32, H16g = 24, WF = 512, HF = 384;
constexpr int HWs8 = W8 * H8;      // 3072
constexpr int HWs16 = W16g * H16g; // 768
constexpr int MP = 64;
constexpr int NTH = 256;
constexpr int BPR = WF / MP;                // 8
constexpr int NBLK = 2 * HF * BPR;          // 6144

constexpr int S = 296;      // row stride (ushorts)
constexpr int SD = S / 2;   // 148 dwords

// d_ws layout (ushort elems)
constexpr int OFF_WC = 0;
constexpr int OFF_W1 = 8192;
constexpr int OFF_W2 = 40960;
constexpr int OFF_WP = 73728;
constexpr int OFF_W3 = 90112;
constexpr int OFF_W4 = 122880;
constexpr int OFF_H0 = 155648;   // K padded 260->272
constexpr int OFF_H1 = 225280;   // 155648 + 272*256
constexpr int OFF_H2 = 258048;   // + 256*128
constexpr int SWZ_TOTAL = 266240; // + 128*64
constexpr int OFF_T = SWZ_TOTAL;           // transposed feat1 (bf16 [B][HW][C])
constexpr int NT_ELEMS = 2 * HWs8 * 128;   // 786432

__device__ __forceinline__ unsigned short f2bf(float f) {  // RNE (prep only)
  union { float f; unsigned u; } v; v.f = f;
  unsigned r = (v.u + 0x7fffu + ((v.u >> 16) & 1u)) >> 16;
  return (unsigned short)r;
}
__device__ __forceinline__ float bflo(unsigned u) {
  return __builtin_bit_cast(float, u << 16);
}
__device__ __forceinline__ float bfhi(unsigned u) {
  return __builtin_bit_cast(float, u & 0xffff0000u);
}
#if defined(__has_builtin)
#if __has_builtin(__builtin_amdgcn_cvt_pk_bf16_f32)
#define HAS_PK_BF16 1
#endif
#if __has_builtin(__builtin_amdgcn_exp2f)
#define HAS_EXP2 1
#endif
#endif
__device__ __forceinline__ unsigned pack2bf(float a, float b) {
#ifdef HAS_PK_BF16
  typedef __bf16 bf2_t __attribute__((ext_vector_type(2)));
  bf2_t r = __builtin_amdgcn_cvt_pk_bf16_f32(a, b);
  return __builtin_bit_cast(unsigned, r);
#else
  unsigned ua = __builtin_bit_cast(unsigned, a) + 0x8000u;
  unsigned ub = __builtin_bit_cast(unsigned, b) + 0x8000u;
  return __builtin_amdgcn_perm(ub, ua, 0x07060302u);
#endif
}
__device__ __forceinline__ float exp2_fast(float x) {
#ifdef HAS_EXP2
  return __builtin_amdgcn_exp2f(x);
#else
  float r;
  asm("v_exp_f32 %0, %1" : "=v"(r) : "v"(x));
  return r;
#endif
}
// tanh-GELU in sigmoid form with log2e pre-folded:
// gelu(x) = x * rcp(1 + exp2(x*(-2.3022082 - 0.10294433*x^2)))
// ~7 VALU (1 TRANS); |err vs erf gelu| ~4e-4 abs.
__device__ __forceinline__ float gelu_fast(float x) {
  float t = fmaf(x * x, -0.10294433f, -2.3022082f);
  float e = exp2_fast(x * t);
  return x * __builtin_amdgcn_rcpf(1.0f + e);
}

// ------------------------------- prep kernel -------------------------------
struct PrepParams { const float* W[9]; const float* f1; unsigned short* ws; };

constexpr int PREP_W_BLOCKS = SWZ_TOTAL / NTH;   // 1040
constexpr int HWT = 32;                          // hw tile for transpose
constexpr int PREP_T_BLOCKS = 2 * (HWs8 / HWT);  // 192

template<int KK, int KP, int NN>
__device__ __forceinline__ void prep_one(const float* __restrict__ W,
                                         unsigned short* __restrict__ dst, int q) {
  int j = q & 7;
  int l = (q >> 3) & 63;
  int r = q >> 9;
  constexpr int nks = KP >> 4;           // compile-time: div -> shift/magic-mul
  int ks = r % nks;
  int mt = r / nks;
  int n = mt * 32 + (l & 31);
  int k = ks * 16 + ((l >> 5) << 3) + j;
  float v = (k < KK) ? W[k * NN + n] : 0.0f;
  dst[q] = f2bf(v);
}

__global__ void prep_kernel(PrepParams pp) {
  __shared__ unsigned short tile[128 * (HWT + 2)];   // 8704 B
  const int blk = blockIdx.x;
  if (blk < PREP_W_BLOCKS) {
    int e = blk * NTH + threadIdx.x;
    unsigned short* ws = pp.ws;
    if (e < OFF_W1)      prep_one<64, 64, 128>(pp.W[0], ws + OFF_WC, e - OFF_WC);
    else if (e < OFF_W2) prep_one<128, 128, 256>(pp.W[1], ws + OFF_W1, e - OFF_W1);
    else if (e < OFF_WP) prep_one<256, 256, 128>(pp.W[2], ws + OFF_W2, e - OFF_W2);
    else if (e < OFF_W3) prep_one<128, 128, 128>(pp.W[3], ws + OFF_WP, e - OFF_WP);
    else if (e < OFF_W4) prep_one<128, 128, 256>(pp.W[4], ws + OFF_W3, e - OFF_W3);
    else if (e < OFF_H0) prep_one<256, 256, 128>(pp.W[5], ws + OFF_W4, e - OFF_W4);
    else if (e < OFF_H1) prep_one<260, 272, 256>(pp.W[6], ws + OFF_H0, e - OFF_H0);
    else if (e < OFF_H2) prep_one<256, 256, 128>(pp.W[7], ws + OFF_H1, e - OFF_H1);
    else                 prep_one<128, 128, 64>(pp.W[8], ws + OFF_H2, e - OFF_H2);
  } else {
    // feat1 [2][128][3072] f32 -> wsT [2][3072][128] bf16, both sides coalesced
    int tb = blk - PREP_W_BLOCKS;
    int b = tb / (HWs8 / HWT);
    int hw0 = (tb % (HWs8 / HWT)) * HWT;
    const float* __restrict__ src = pp.f1 + (size_t)b * 128 * HWs8;
    unsigned short* __restrict__ dst = pp.ws + OFF_T + (size_t)b * HWs8 * 128;
    int hw = threadIdx.x & (HWT - 1);
    int cg = threadIdx.x >> 5;          // 0..7
#pragma unroll
    for (int c0 = 0; c0 < 16; ++c0) {
      int c = c0 * 8 + cg;
      tile[c * (HWT + 2) + hw] = f2bf(src[c * HWs8 + hw0 + hw]);
    }
    __syncthreads();
    int cD = threadIdx.x & 63;          // dword col = channels 2cD,2cD+1
    int hg = threadIdx.x >> 6;          // 0..3
#pragma unroll
    for (int h0 = 0; h0 < HWT / 4; ++h0) {
      int hh = h0 * 4 + hg;
      unsigned lo = tile[(2 * cD) * (HWT + 2) + hh];
      unsigned hi = tile[(2 * cD + 1) * (HWT + 2) + hh];
      *(unsigned*)(dst + (hw0 + hh) * 128 + 2 * cD) = lo | (hi << 16);
    }
  }
}

// ------------------------------ main kernel --------------------------------
struct Params {
  const float* feat_s8; const float* feat_s16;
  const float* ctx_s8;  const float* coarse;
  const float* bc; const float* g1; const float* b1; const float* b2;
  const float* bp; const float* g2; const float* b3; const float* b4;
  const float* h0b; const float* h1b; const float* h2b;
  const float* h3w; const float* h3b;
  const unsigned short* ws;
  const unsigned short* wsT;
  float* out;
};

__device__ __forceinline__ void bilin_setup(float g, int Sg, int& i0, int& i1, float& w) {
  float s = (g + 1.0f) * (0.5f * Sg) - 0.5f;
  float f = floorf(s);
  w = s - f;
  int a = (int)f;
  i0 = min(max(a, 0), Sg - 1);
  i1 = min(max(a + 1, 0), Sg - 1);
}

// Patch index remap into buf's dead columns (float view):
// MAP 0: dword cols [32:64)  (ushort [64:128))   cap 2048 floats
// MAP 1: dword cols [128:144) (ushort [256:288)) cap 1024 floats
template<int MAP>
__device__ __forceinline__ int pmap(int n) {
  if (MAP == 0) return ((n >> 5) * SD) + 32 + (n & 31);
  else          return ((n >> 4) * SD) + 128 + (n & 15);
}

// 32x32x16 MFMA layer, K compile-time (full unroll).
template<int MT, int NT, int EP, bool SYNC, int K>
__device__ __forceinline__ void mfma_layer(
    const unsigned short* __restrict__ Wsw,
    const float* __restrict__ bias,
    const unsigned short* actIn,
    unsigned short* actOut,
    const float* __restrict__ gate,
    const unsigned short* res)
{
  const int t = threadIdx.x;
  const int l = t & 63;
  const int wv = t >> 6;
  constexpr int nks = K >> 4;
  const int mt0 = (NT == 2) ? wv * MT : (wv >> 1);
  const int ntb = (NT == 2) ? 0 : (wv & 1);
  const int lh = l >> 5;
  const int ll = l & 31;

  f32x16 acc[MT][NT];
#pragma unroll
  for (int m = 0; m < MT; ++m) {
#pragma unroll
    for (int g = 0; g < 4; ++g) {
      const int f0 = (mt0 + m) * 32 + g * 8 + (lh << 2);
      const float4 bv = *(const float4*)(bias + f0);
#pragma unroll
      for (int nt = 0; nt < NT; ++nt) {
        acc[m][nt][g * 4 + 0] = bv.x; acc[m][nt][g * 4 + 1] = bv.y;
        acc[m][nt][g * 4 + 2] = bv.z; acc[m][nt][g * 4 + 3] = bv.w;
      }
    }
  }

  const unsigned short* bbase = actIn + (ntb * 32 + ll) * S + (lh << 3);
  const unsigned short* abase = Wsw + (size_t)mt0 * nks * 512 + l * 8;

  __builtin_amdgcn_s_setprio(1);
#pragma unroll
  for (int ks = 0; ks < nks; ++ks) {
    bf16x8 B[NT];
#pragma unroll
    for (int nt = 0; nt < NT; ++nt)
      B[nt] = *(const bf16x8*)(bbase + nt * 32 * S + ks * 16);
#pragma unroll
    for (int m = 0; m < MT; ++m) {
      bf16x8 A = *(const bf16x8*)(abase + (m * nks + ks) * 512);
#pragma unroll
      for (int nt = 0; nt < NT; ++nt)
        acc[m][nt] = __builtin_amdgcn_mfma_f32_32x32x16_bf16(A, B[nt], acc[m][nt], 0, 0, 0);
    }
  }
  __builtin_amdgcn_s_setprio(0);

  if (SYNC) __syncthreads();

#pragma unroll
  for (int m = 0; m < MT; ++m) {
#pragma unroll
    for (int g = 0; g < 4; ++g) {
      const int f0 = (mt0 + m) * 32 + g * 8 + (lh << 2);
      float4 gv;
      if (EP == 3) {
        float4 gg = *(const float4*)(gate + f0);
        gv.x = __builtin_amdgcn_rcpf(1.0f + exp2_fast(gg.x * -1.44269504f));
        gv.y = __builtin_amdgcn_rcpf(1.0f + exp2_fast(gg.y * -1.44269504f));
        gv.z = __builtin_amdgcn_rcpf(1.0f + exp2_fast(gg.z * -1.44269504f));
        gv.w = __builtin_amdgcn_rcpf(1.0f + exp2_fast(gg.w * -1.44269504f));
      }
#pragma unroll
      for (int nt = 0; nt < NT; ++nt) {
        const int pt = (ntb + nt) * 32 + ll;
        float v[4];
        v[0] = acc[m][nt][g * 4 + 0]; v[1] = acc[m][nt][g * 4 + 1];
        v[2] = acc[m][nt][g * 4 + 2]; v[3] = acc[m][nt][g * 4 + 3];
        if (EP == 1) {
#pragma unroll
          for (int r = 0; r < 4; ++r) v[r] = gelu_fast(v[r]);
        } else if (EP == 2) {
#pragma unroll
          for (int r = 0; r < 4; ++r) v[r] = fmaxf(v[r], 0.0f);
        } else if (EP == 3) {
          uint2 rv = *(const uint2*)(res + pt * S + f0);
          v[0] = fmaf(gv.x, v[0], bflo(rv.x));
          v[1] = fmaf(gv.y, v[1], bfhi(rv.x));
          v[2] = fmaf(gv.z, v[2], bflo(rv.y));
          v[3] = fmaf(gv.w, v[3], bfhi(rv.y));
        }
        uint2 pk;
        pk.x = pack2bf(v[0], v[1]);
        pk.y = pack2bf(v[2], v[3]);
        *(uint2*)(actOut + pt * S + f0) = pk;
      }
    }
  }
}

// stage a y-lerped patch into a remapped region of buf
template<int NCOL, int NCH, int MAP>
__device__ void stage_patch(const float* __restrict__ fm, int HW, int Wimg,
                            int base, int y0, int y1, float wy, float* bufF)
{
  const int items = NCOL * NCH;
  for (int e = threadIdx.x; e < items; e += NTH) {
    int ch = e / NCOL, col = e - ch * NCOL;
    int ca = min(base + col, Wimg - 1);
    const float* pp = fm + ch * HW;
    float v0 = pp[y0 * Wimg + ca];
    float v1 = pp[y1 * Wimg + ca];
    bufF[pmap<MAP>(col * (NCH + 2) + ch)] = fmaf(wy, v1 - v0, v0);
  }
}

// x-lerp from remapped patch into bf16 B-layout columns of buf
template<int PAIRS, int MAP, int CST>
__device__ void xlerp_tile(const float* __restrict__ bufF, const int* pcB, int shift,
                           const float* wxA, unsigned short* outBuf, int colOff)
{
  const int items = MP * PAIRS;
  for (int it = threadIdx.x; it < items; it += NTH) {
    int pr = it & (PAIRS - 1);
    int pt = it / PAIRS;
    int pc = pcB[pt] >> shift;
    int c0 = pc & 15, c1 = (pc >> 4) & 15;
    float wx = wxA[pt];
    float2 a = *(const float2*)(bufF + pmap<MAP>(c0 * CST + pr * 2));
    float2 b = *(const float2*)(bufF + pmap<MAP>(c1 * CST + pr * 2));
    float r0 = fmaf(wx, b.x - a.x, a.x);
    float r1 = fmaf(wx, b.y - a.y, a.y);
    *(unsigned*)(outBuf + pt * S + colOff + pr * 2) = pack2bf(r0, r1);
  }
}

// coalesced warped gather from transposed bf16 feat1 ([HW][C]);
// uint4-vectorized: 8 channels per item, one ds_write_b128 per item
__device__ void gather_tile_T(const unsigned short* __restrict__ T,
    const int* offT0, const int* offT1, const float* wxA, const float* wyA,
    unsigned short* outBuf, int colOff)
{
  for (int it = threadIdx.x; it < MP * 16; it += NTH) {
    int pt = it >> 4;
    int c8 = (it & 15) * 8;            // channel base (8 channels/item)
    int e0 = offT0[pt], e1 = offT1[pt];
    int du = (e0 & 1) << 7;            // 0 or 128 (channel stride per +1 x)
    int o00 = e0 & ~1, o10 = e1 & ~1;
    float wx = wxA[pt], wy = wyA[pt];
    uint4 a00 = *(const uint4*)(T + o00 + c8);
    uint4 a01 = *(const uint4*)(T + o00 + du + c8);
    uint4 a10 = *(const uint4*)(T + o10 + c8);
    uint4 a11 = *(const uint4*)(T + o10 + du + c8);
    float w11 = wx * wy;
    float w01 = wx - w11, w10 = wy - w11, w00 = 1.0f - wx - wy + w11;
    uint4 res;
    const unsigned* p00 = (const unsigned*)&a00;
    const unsigned* p01 = (const unsigned*)&a01;
    const unsigned* p10 = (const unsigned*)&a10;
    const unsigned* p11 = (const unsigned*)&a11;
    unsigned* pr = (unsigned*)&res;
#pragma unroll
    for (int q = 0; q < 4; ++q) {
      float r0 = w00 * bflo(p00[q]) + w01 * bflo(p01[q])
               + w10 * bflo(p10[q]) + w11 * bflo(p11[q]);
      float r1 = w00 * bfhi(p00[q]) + w01 * bfhi(p01[q])
               + w10 * bfhi(p10[q]) + w11 * bfhi(p11[q]);
      pr[q] = pack2bf(r0, r1);
    }
    *(uint4*)(outBuf + pt * S + colOff + c8) = res;   // 16B aligned: S*2=592=37*16
  }
}

__global__ __launch_bounds__(256, 4)
void ifd_kernel(Params p)
{
  __shared__ __align__(16) unsigned short buf[MP * S];   // 37888 B
  __shared__ int offT0[MP], offT1[MP];                    // 512 B
  __shared__ int pcBoth[MP];                              // 256 B
  __shared__ float w8x[MP], w16x[MP], wWx[MP], wWy[MP];   // 1024 B
  __shared__ float caxA[MP], cayA[MP];                    // 512 B
  __shared__ int uy8_0, uy8_1, uy16_0, uy16_1, ubase8, ubase16;
  __shared__ float uwy8, uwy16;

  float* bufF = (float*)buf;

  const int blk = blockIdx.x;
  const int bb = blk / (HF * BPR);
  const int r = blk % (HF * BPR);
  const int y = r >> 3;
  const int xb = (r & (BPR - 1)) * MP;
  const int t = threadIdx.x;
  const float lim = 1.0f - 1e-6f;

  if (t < MP) {
    const int i = t;
    const int x = xb + i;
    float gx = (x + 0.5f) * (2.0f / WF) - 1.0f;
    float gy = (y + 0.5f) * (2.0f / HF) - 1.0f;
    gx = fminf(fmaxf(gx, -lim), lim);
    gy = fminf(fmaxf(gy, -lim), lim);

    float gx0 = fminf(fmaxf((xb + 0.5f) * (2.0f / WF) - 1.0f, -lim), lim);
    int base8 = min(max((int)floorf((gx0 + 1.0f) * 32.0f - 0.5f), 0), W8 - 1);
    int base16 = min(max((int)floorf((gx0 + 1.0f) * 16.0f - 0.5f), 0), W16g - 1);

    int x0, x1, y0, y1; float wx, wy;
    bilin_setup(gx, W8, x0, x1, wx);
    bilin_setup(gy, H8, y0, y1, wy);
    w8x[i] = wx;
    int o00 = y0 * W8 + x0, o01 = y0 * W8 + x1;
    int o10 = y1 * W8 + x0, o11 = y1 * W8 + x1;

    int a0, a1, b0i, b1i; float vx, vy;
    bilin_setup(gx, W16g, a0, a1, vx);
    bilin_setup(gy, H16g, b0i, b1i, vy);
    w16x[i] = vx;
    pcBoth[i] = (x0 - base8) | ((x1 - base8) << 4)
              | ((a0 - base16) << 8) | ((a1 - base16) << 12);

    if (i == 0) {
      uy8_0 = y0; uy8_1 = y1; uwy8 = wy;
      uy16_0 = b0i; uy16_1 = b1i; uwy16 = vy;
      ubase8 = base8; ubase16 = base16;
    }

    const float* cf = p.coarse + bb * 2 * HWs8;
    float c00 = cf[o00], c01 = cf[o01], c10 = cf[o10], c11 = cf[o11];
    float cx0 = fmaf(wx, c01 - c00, c00), cx1 = fmaf(wx, c11 - c10, c10);
    float cfx = fmaf(wy, cx1 - cx0, cx0);
    const float* cf2 = cf + HWs8;
    c00 = cf2[o00]; c01 = cf2[o01]; c10 = cf2[o10]; c11 = cf2[o11];
    cx0 = fmaf(wx, c01 - c00, c00); cx1 = fmaf(wx, c11 - c10, c10);
    float cfy = fmaf(wy, cx1 - cx0, cx0);
    float cax = cfx * 8.0f, cay = cfy * 8.0f;
    caxA[i] = cax; cayA[i] = cay;

    float wxn = gx + cax * (2.0f / WF);
    float wyn = gy + cay * (2.0f / HF);
    wxn = fminf(fmaxf(wxn, -lim), lim);
    wyn = fminf(fmaxf(wyn, -lim), lim);
    int u0, u1, v0, v1; float uw, vw;
    bilin_setup(wxn, W8, u0, u1, uw);
    bilin_setup(wyn, H8, v0, v1, vw);
    int du = u1 - u0;   // 0 or 1
    offT0[i] = ((v0 * W8 + u0) << 7) | du;
    offT1[i] = ((v1 * W8 + u0) << 7) | du;
    wWx[i] = uw; wWy[i] = vw;
  }
  __syncthreads();

  // stage f8 -> MAP0; ctx -> MAP1
  stage_patch<10, 128, 0>(p.feat_s8 + bb * 128 * HWs8, HWs8, W8,
                          ubase8, uy8_0, uy8_1, uwy8, bufF);
  stage_patch<10, 64, 1>(p.ctx_s8 + bb * 64 * HWs8, HWs8, W8,
                         ubase8, uy8_0, uy8_1, uwy8, bufF);
  __syncthreads();
  xlerp_tile<64, 0, 130>(bufF, pcBoth, 0, w8x, buf, 128);  // f8  -> [128:256)
  xlerp_tile<32, 1, 66>(bufF, pcBoth, 0, w8x, buf, 0);     // ctx -> [0:64)
  __syncthreads();

  // Wc: [0:64) K=64 -> [128:256), residual same cols
  mfma_layer<1, 2, 3, false, 64>(p.ws + OFF_WC, p.bc, buf, buf + 128, p.g1, buf + 128);
  // overlap: stage f16 patch -> MAP1
  stage_patch<6, 128, 1>(p.feat_s16 + bb * 128 * HWs16, HWs16, W16g,
                         ubase16, uy16_0, uy16_1, uwy16, bufF);
  __syncthreads();
  // W1: [128:256) K=128 -> [0:256)
  mfma_layer<2, 2, 1, true, 128>(p.ws + OFF_W1, p.b1, buf + 128, buf, nullptr, nullptr);
  __syncthreads();
  // W2: [0:256) K=256 -> [0:128); then f16 x-lerp -> [128:256)
  mfma_layer<1, 2, 0, true, 256>(p.ws + OFF_W2, p.b2, buf, buf, nullptr, nullptr);
  xlerp_tile<64, 1, 130>(bufF, pcBoth, 8, w16x, buf, 128);
  __syncthreads();
  // Wp: [0:128) -> [128:256), residual same cols
  mfma_layer<1, 2, 3, false, 128>(p.ws + OFF_WP, p.bp, buf, buf + 128, p.g2, buf + 128);
  __syncthreads();
  // W3: [128:256) K=128 -> [0:256)
  mfma_layer<2, 2, 1, true, 128>(p.ws + OFF_W3, p.b3, buf + 128, buf, nullptr, nullptr);
  __syncthreads();
  // W4: [0:256) K=256 -> [0:128); gather -> [128:256); extras -> [256:272)
  mfma_layer<1, 2, 0, true, 256>(p.ws + OFF_W4, p.b4, buf, buf, nullptr, nullptr);
  gather_tile_T(p.wsT + bb * HWs8 * 128, offT0, offT1, wWx, wWy, buf, 128);
  for (int idx = t; idx < MP * 8; idx += NTH) {
    int row = idx >> 3, c = idx & 7;
    unsigned val = 0;
    if (c == 0) {
      float gx = fminf(fmaxf((xb + row + 0.5f) * (2.0f / WF) - 1.0f, -lim), lim);
      float gy = fminf(fmaxf((y + 0.5f) * (2.0f / HF) - 1.0f, -lim), lim);
      val = pack2bf(gx, gy);
    } else if (c == 1) {
      val = pack2bf(caxA[row] * (1.0f / WF), cayA[row] * (1.0f / HF));
    }
    *(unsigned*)(buf + row * S + 256 + c * 2) = val;
  }
  __syncthreads();
  // flow head, all in-place (H0 K padded 260 -> 272)
  mfma_layer<2, 2, 2, true, 272>(p.ws + OFF_H0, p.h0b, buf, buf, nullptr, nullptr);
  __syncthreads();
  mfma_layer<1, 2, 2, true, 256>(p.ws + OFF_H1, p.h1b, buf, buf, nullptr, nullptr);
  __syncthreads();
  mfma_layer<1, 1, 2, true, 128>(p.ws + OFF_H2, p.h2b, buf, buf, nullptr, nullptr);
  __syncthreads();

  // final 64->2 + output (fp32); h3w from global (wave-uniform -> s_loads)
  if (t < 128) {
    int i = t & 63, comp = t >> 6;
    float acc = p.h3b[comp];
    const unsigned short* rowp = buf + i * S;
    const float* wp = p.h3w + comp;
#pragma unroll
    for (int k8 = 0; k8 < 8; ++k8) {
      uint4 av = *(const uint4*)(rowp + k8 * 8);
      const float* w8p = wp + k8 * 16;
      acc = fmaf(bflo(av.x), w8p[0], acc);
      acc = fmaf(bfhi(av.x), w8p[2], acc);
      acc = fmaf(bflo(av.y), w8p[4], acc);
      acc = fmaf(bfhi(av.y), w8p[6], acc);
      acc = fmaf(bflo(av.z), w8p[8], acc);
      acc = fmaf(bfhi(av.z), w8p[10], acc);
      acc = fmaf(bflo(av.w), w8p[12], acc);
      acc = fmaf(bfhi(av.w), w8p[14], acc);
    }
    float flow = (comp ? cayA[i] : caxA[i]) + acc * (comp ? (float)HF : (float)WF);
    p.out[((bb * 2 + comp) * HF + y) * WF + xb + i] = flow;
  }
}

extern "C" void kernel_launch(void* const* d_in, const int* in_sizes, int n_in,
                              void* d_out, int out_size, void* d_ws, size_t ws_size,
                              hipStream_t stream) {
  PrepParams pp;
  pp.W[0] = (const float*)d_in[6];   // Wc
  pp.W[1] = (const float*)d_in[9];   // W1
  pp.W[2] = (const float*)d_in[11];  // W2
  pp.W[3] = (const float*)d_in[13];  // Wp
  pp.W[4] = (const float*)d_in[16];  // W3
  pp.W[5] = (const float*)d_in[18];  // W4
  pp.W[6] = (const float*)d_in[20];  // hw0
  pp.W[7] = (const float*)d_in[22];  // hw1
  pp.W[8] = (const float*)d_in[24];  // hw2
  pp.f1   = (const float*)d_in[2];   // feat1_s8
  pp.ws = (unsigned short*)d_ws;
  hipLaunchKernelGGL(prep_kernel, dim3(PREP_W_BLOCKS + PREP_T_BLOCKS), dim3(NTH),
                     0, stream, pp);

  Params p;
  p.feat_s8  = (const float*)d_in[1];
  p.feat_s16 = (const float*)d_in[3];
  p.ctx_s8   = (const float*)d_in[4];
  p.coarse   = (const float*)d_in[5];
  p.bc  = (const float*)d_in[7];
  p.g1  = (const float*)d_in[8];
  p.b1  = (const float*)d_in[10];
  p.b2  = (const float*)d_in[12];
  p.bp  = (const float*)d_in[14];
  p.g2  = (const float*)d_in[15];
  p.b3  = (const float*)d_in[17];
  p.b4  = (const float*)d_in[19];
  p.h0b = (const float*)d_in[21];
  p.h1b = (const float*)d_in[23];
  p.h2b = (const float*)d_in[25];
  p.h3w = (const float*)d_in[26];
  p.h3b = (const float*)d_in[27];
  p.ws  = (const unsigned short*)d_ws;
  p.wsT = (const unsigned short*)d_ws + OFF_T;
  p.out = (float*)d_out;

  hipLaunchKernelGGL(ifd_kernel, dim3(NBLK), dim3(NTH), 0, stream, p);
}

// Round 2
// 417.814 us; speedup vs baseline: 1.1035x; 1.0350x over previous
//
#include <hip/hip_runtime.h>
#include <math.h>

// ---------------------------------------------------------------------------
// ImplicitFlowDecoder — R11:
//  - lgkm-only barriers (no vmcnt(0) drain): all cross-wave comms are LDS-only,
//    so s_waitcnt lgkmcnt(0) + s_barrier suffices; global loads stay in flight
//    across barriers.
//  - explicit A-fragment prefetch: next layer's first 4 A tiles issued before
//    each barrier (16 VGPR), hiding L2 latency at every layer start.
//  - bias moved to epilogue (acc zero-init): first MFMA waits only on ds_read.
// R10: fused constexpr prep + coalesced transpose, H0 K=272, uint4 gather,
//      exp2-folded gelu, s_setprio. R8/R9: see history.
// ---------------------------------------------------------------------------

typedef short bf16x8 __attribute__((ext_vector_type(8)));
typedef float f32x16 __attribute__((ext_vector_type(16)));

constexpr int W8 = 64, H8 = 48, W16g = 32, H16g = 24, WF = 512, HF = 384;
constexpr int HWs8 = W8 * H8;      // 3072
constexpr int HWs16 = W16g * H16g; // 768
constexpr int MP = 64;
constexpr int NTH = 256;
constexpr int BPR = WF / MP;                // 8
constexpr int NBLK = 2 * HF * BPR;          // 6144

constexpr int S = 296;      // row stride (ushorts)
constexpr int SD = S / 2;   // 148 dwords

// d_ws layout (ushort elems)
constexpr int OFF_WC = 0;
constexpr int OFF_W1 = 8192;
constexpr int OFF_W2 = 40960;
constexpr int OFF_WP = 73728;
constexpr int OFF_W3 = 90112;
constexpr int OFF_W4 = 122880;
constexpr int OFF_H0 = 155648;   // K padded 260->272
constexpr int OFF_H1 = 225280;   // 155648 + 272*256
constexpr int OFF_H2 = 258048;   // + 256*128
constexpr int SWZ_TOTAL = 266240; // + 128*64
constexpr int OFF_T = SWZ_TOTAL;           // transposed feat1 (bf16 [B][HW][C])
constexpr int NT_ELEMS = 2 * HWs8 * 128;   // 786432

__device__ __forceinline__ unsigned short f2bf(float f) {  // RNE (prep only)
  union { float f; unsigned u; } v; v.f = f;
  unsigned r = (v.u + 0x7fffu + ((v.u >> 16) & 1u)) >> 16;
  return (unsigned short)r;
}
__device__ __forceinline__ float bflo(unsigned u) {
  return __builtin_bit_cast(float, u << 16);
}
__device__ __forceinline__ float bfhi(unsigned u) {
  return __builtin_bit_cast(float, u & 0xffff0000u);
}
#if defined(__has_builtin)
#if __has_builtin(__builtin_amdgcn_cvt_pk_bf16_f32)
#define HAS_PK_BF16 1
#endif
#if __has_builtin(__builtin_amdgcn_exp2f)
#define HAS_EXP2 1
#endif
#endif
__device__ __forceinline__ unsigned pack2bf(float a, float b) {
#ifdef HAS_PK_BF16
  typedef __bf16 bf2_t __attribute__((ext_vector_type(2)));
  bf2_t r = __builtin_amdgcn_cvt_pk_bf16_f32(a, b);
  return __builtin_bit_cast(unsigned, r);
#else
  unsigned ua = __builtin_bit_cast(unsigned, a) + 0x8000u;
  unsigned ub = __builtin_bit_cast(unsigned, b) + 0x8000u;
  return __builtin_amdgcn_perm(ub, ua, 0x07060302u);
#endif
}
__device__ __forceinline__ float exp2_fast(float x) {
#ifdef HAS_EXP2
  return __builtin_amdgcn_exp2f(x);
#else
  float r;
  asm("v_exp_f32 %0, %1" : "=v"(r) : "v"(x));
  return r;
#endif
}
// tanh-GELU in sigmoid form with log2e pre-folded:
// gelu(x) = x * rcp(1 + exp2(x*(-2.3022082 - 0.10294433*x^2)))
__device__ __forceinline__ float gelu_fast(float x) {
  float t = fmaf(x * x, -0.10294433f, -2.3022082f);
  float e = exp2_fast(x * t);
  return x * __builtin_amdgcn_rcpf(1.0f + e);
}

// LDS-only barrier: no vmcnt(0) drain (no cross-thread global deps in-kernel).
// Global loads issued before this stay in flight across the barrier.
__device__ __forceinline__ void barrier_lds() {
  asm volatile("s_waitcnt lgkmcnt(0)" ::: "memory");
  __builtin_amdgcn_s_barrier();
  asm volatile("" ::: "memory");
}

// ------------------------------- prep kernel -------------------------------
struct PrepParams { const float* W[9]; const float* f1; unsigned short* ws; };

constexpr int PREP_W_BLOCKS = SWZ_TOTAL / NTH;   // 1040
constexpr int HWT = 32;                          // hw tile for transpose
constexpr int PREP_T_BLOCKS = 2 * (HWs8 / HWT);  // 192

template<int KK, int KP, int NN>
__device__ __forceinline__ void prep_one(const float* __restrict__ W,
                                         unsigned short* __restrict__ dst, int q) {
  int j = q & 7;
  int l = (q >> 3) & 63;
  int r = q >> 9;
  constexpr int nks = KP >> 4;
  int ks = r % nks;
  int mt = r / nks;
  int n = mt * 32 + (l & 31);
  int k = ks * 16 + ((l >> 5) << 3) + j;
  float v = (k < KK) ? W[k * NN + n] : 0.0f;
  dst[q] = f2bf(v);
}

__global__ void prep_kernel(PrepParams pp) {
  __shared__ unsigned short tile[128 * (HWT + 2)];   // 8704 B
  const int blk = blockIdx.x;
  if (blk < PREP_W_BLOCKS) {
    int e = blk * NTH + threadIdx.x;
    unsigned short* ws = pp.ws;
    if (e < OFF_W1)      prep_one<64, 64, 128>(pp.W[0], ws + OFF_WC, e - OFF_WC);
    else if (e < OFF_W2) prep_one<128, 128, 256>(pp.W[1], ws + OFF_W1, e - OFF_W1);
    else if (e < OFF_WP) prep_one<256, 256, 128>(pp.W[2], ws + OFF_W2, e - OFF_W2);
    else if (e < OFF_W3) prep_one<128, 128, 128>(pp.W[3], ws + OFF_WP, e - OFF_WP);
    else if (e < OFF_W4) prep_one<128, 128, 256>(pp.W[4], ws + OFF_W3, e - OFF_W3);
    else if (e < OFF_H0) prep_one<256, 256, 128>(pp.W[5], ws + OFF_W4, e - OFF_W4);
    else if (e < OFF_H1) prep_one<260, 272, 256>(pp.W[6], ws + OFF_H0, e - OFF_H0);
    else if (e < OFF_H2) prep_one<256, 256, 128>(pp.W[7], ws + OFF_H1, e - OFF_H1);
    else                 prep_one<128, 128, 64>(pp.W[8], ws + OFF_H2, e - OFF_H2);
  } else {
    // feat1 [2][128][3072] f32 -> wsT [2][3072][128] bf16, both sides coalesced
    int tb = blk - PREP_W_BLOCKS;
    int b = tb / (HWs8 / HWT);
    int hw0 = (tb % (HWs8 / HWT)) * HWT;
    const float* __restrict__ src = pp.f1 + (size_t)b * 128 * HWs8;
    unsigned short* __restrict__ dst = pp.ws + OFF_T + (size_t)b * HWs8 * 128;
    int hw = threadIdx.x & (HWT - 1);
    int cg = threadIdx.x >> 5;          // 0..7
#pragma unroll
    for (int c0 = 0; c0 < 16; ++c0) {
      int c = c0 * 8 + cg;
      tile[c * (HWT + 2) + hw] = f2bf(src[c * HWs8 + hw0 + hw]);
    }
    __syncthreads();
    int cD = threadIdx.x & 63;          // dword col = channels 2cD,2cD+1
    int hg = threadIdx.x >> 6;          // 0..3
#pragma unroll
    for (int h0 = 0; h0 < HWT / 4; ++h0) {
      int hh = h0 * 4 + hg;
      unsigned lo = tile[(2 * cD) * (HWT + 2) + hh];
      unsigned hi = tile[(2 * cD + 1) * (HWT + 2) + hh];
      *(unsigned*)(dst + (hw0 + hh) * 128 + 2 * cD) = lo | (hi << 16);
    }
  }
}

// ------------------------------ main kernel --------------------------------
struct Params {
  const float* feat_s8; const float* feat_s16;
  const float* ctx_s8;  const float* coarse;
  const float* bc; const float* g1; const float* b1; const float* b2;
  const float* bp; const float* g2; const float* b3; const float* b4;
  const float* h0b; const float* h1b; const float* h2b;
  const float* h3w; const float* h3b;
  const unsigned short* ws;
  const unsigned short* wsT;
  float* out;
};

__device__ __forceinline__ void bilin_setup(float g, int Sg, int& i0, int& i1, float& w) {
  float s = (g + 1.0f) * (0.5f * Sg) - 0.5f;
  float f = floorf(s);
  w = s - f;
  int a = (int)f;
  i0 = min(max(a, 0), Sg - 1);
  i1 = min(max(a + 1, 0), Sg - 1);
}

// Patch index remap into buf's dead columns (float view)
template<int MAP>
__device__ __forceinline__ int pmap(int n) {
  if (MAP == 0) return ((n >> 5) * SD) + 32 + (n & 31);
  else          return ((n >> 4) * SD) + 128 + (n & 15);
}

// prefetch the next layer's first 4 A tiles (consumption order: ks-major, m-minor)
template<int MTN, int NTN, int NKSN>
__device__ __forceinline__ void prefetchA(const unsigned short* __restrict__ Wsw,
                                          bf16x8* pf) {
  const int t = threadIdx.x;
  const int l = t & 63;
  const int wv = t >> 6;
  const int mt0 = (NTN == 2) ? wv * MTN : (wv >> 1);
  const unsigned short* ab = Wsw + (size_t)mt0 * NKSN * 512 + l * 8;
  if (MTN == 1) {
#pragma unroll
    for (int i = 0; i < 4; ++i) pf[i] = *(const bf16x8*)(ab + i * 512);
  } else {
    pf[0] = *(const bf16x8*)(ab);
    pf[1] = *(const bf16x8*)(ab + (size_t)NKSN * 512);
    pf[2] = *(const bf16x8*)(ab + 512);
    pf[3] = *(const bf16x8*)(ab + (size_t)NKSN * 512 + 512);
  }
}

// 32x32x16 MFMA layer, K compile-time (full unroll). First 4 A tiles from pf.
// Bias applied in epilogue (acc zero-init) so first MFMA waits only on ds_read.
template<int MT, int NT, int EP, bool SYNC, int K>
__device__ __forceinline__ void mfma_layer(
    const unsigned short* __restrict__ Wsw,
    const float* __restrict__ bias,
    const unsigned short* actIn,
    unsigned short* actOut,
    const float* __restrict__ gate,
    const unsigned short* res,
    const bf16x8* pf)
{
  const int t = threadIdx.x;
  const int l = t & 63;
  const int wv = t >> 6;
  constexpr int nks = K >> 4;
  const int mt0 = (NT == 2) ? wv * MT : (wv >> 1);
  const int ntb = (NT == 2) ? 0 : (wv & 1);
  const int lh = l >> 5;
  const int ll = l & 31;

  f32x16 acc[MT][NT];
#pragma unroll
  for (int m = 0; m < MT; ++m)
#pragma unroll
    for (int nt = 0; nt < NT; ++nt)
#pragma unroll
      for (int e = 0; e < 16; ++e)
        acc[m][nt][e] = 0.0f;

  const unsigned short* bbase = actIn + (ntb * 32 + ll) * S + (lh << 3);
  const unsigned short* abase = Wsw + (size_t)mt0 * nks * 512 + l * 8;

  __builtin_amdgcn_s_setprio(1);
#pragma unroll
  for (int ks = 0; ks < nks; ++ks) {
    bf16x8 B[NT];
#pragma unroll
    for (int nt = 0; nt < NT; ++nt)
      B[nt] = *(const bf16x8*)(bbase + nt * 32 * S + ks * 16);
#pragma unroll
    for (int m = 0; m < MT; ++m) {
      bf16x8 A;
      if (ks * MT + m < 4) A = pf[ks * MT + m];
      else A = *(const bf16x8*)(abase + (m * nks + ks) * 512);
#pragma unroll
      for (int nt = 0; nt < NT; ++nt)
        acc[m][nt] = __builtin_amdgcn_mfma_f32_32x32x16_bf16(A, B[nt], acc[m][nt], 0, 0, 0);
    }
  }
  __builtin_amdgcn_s_setprio(0);

  if (SYNC) barrier_lds();

#pragma unroll
  for (int m = 0; m < MT; ++m) {
#pragma unroll
    for (int g = 0; g < 4; ++g) {
      const int f0 = (mt0 + m) * 32 + g * 8 + (lh << 2);
      const float4 bv = *(const float4*)(bias + f0);
      float4 gv;
      if (EP == 3) {
        float4 gg = *(const float4*)(gate + f0);
        gv.x = __builtin_amdgcn_rcpf(1.0f + exp2_fast(gg.x * -1.44269504f));
        gv.y = __builtin_amdgcn_rcpf(1.0f + exp2_fast(gg.y * -1.44269504f));
        gv.z = __builtin_amdgcn_rcpf(1.0f + exp2_fast(gg.z * -1.44269504f));
        gv.w = __builtin_amdgcn_rcpf(1.0f + exp2_fast(gg.w * -1.44269504f));
      }
#pragma unroll
      for (int nt = 0; nt < NT; ++nt) {
        const int pt = (ntb + nt) * 32 + ll;
        float v[4];
        v[0] = acc[m][nt][g * 4 + 0] + bv.x;
        v[1] = acc[m][nt][g * 4 + 1] + bv.y;
        v[2] = acc[m][nt][g * 4 + 2] + bv.z;
        v[3] = acc[m][nt][g * 4 + 3] + bv.w;
        if (EP == 1) {
#pragma unroll
          for (int r = 0; r < 4; ++r) v[r] = gelu_fast(v[r]);
        } else if (EP == 2) {
#pragma unroll
          for (int r = 0; r < 4; ++r) v[r] = fmaxf(v[r], 0.0f);
        } else if (EP == 3) {
          uint2 rv = *(const uint2*)(res + pt * S + f0);
          v[0] = fmaf(gv.x, v[0], bflo(rv.x));
          v[1] = fmaf(gv.y, v[1], bfhi(rv.x));
          v[2] = fmaf(gv.z, v[2], bflo(rv.y));
          v[3] = fmaf(gv.w, v[3], bfhi(rv.y));
        }
        uint2 pk;
        pk.x = pack2bf(v[0], v[1]);
        pk.y = pack2bf(v[2], v[3]);
        *(uint2*)(actOut + pt * S + f0) = pk;
      }
    }
  }
}

// stage a y-lerped patch into a remapped region of buf
template<int NCOL, int NCH, int MAP>
__device__ void stage_patch(const float* __restrict__ fm, int HW, int Wimg,
                            int base, int y0, int y1, float wy, float* bufF)
{
  const int items = NCOL * NCH;
  for (int e = threadIdx.x; e < items; e += NTH) {
    int ch = e / NCOL, col = e - ch * NCOL;
    int ca = min(base + col, Wimg - 1);
    const float* pp = fm + ch * HW;
    float v0 = pp[y0 * Wimg + ca];
    float v1 = pp[y1 * Wimg + ca];
    bufF[pmap<MAP>(col * (NCH + 2) + ch)] = fmaf(wy, v1 - v0, v0);
  }
}

// x-lerp from remapped patch into bf16 B-layout columns of buf
template<int PAIRS, int MAP, int CST>
__device__ void xlerp_tile(const float* __restrict__ bufF, const int* pcB, int shift,
                           const float* wxA, unsigned short* outBuf, int colOff)
{
  const int items = MP * PAIRS;
  for (int it = threadIdx.x; it < items; it += NTH) {
    int pr = it & (PAIRS - 1);
    int pt = it / PAIRS;
    int pc = pcB[pt] >> shift;
    int c0 = pc & 15, c1 = (pc >> 4) & 15;
    float wx = wxA[pt];
    float2 a = *(const float2*)(bufF + pmap<MAP>(c0 * CST + pr * 2));
    float2 b = *(const float2*)(bufF + pmap<MAP>(c1 * CST + pr * 2));
    float r0 = fmaf(wx, b.x - a.x, a.x);
    float r1 = fmaf(wx, b.y - a.y, a.y);
    *(unsigned*)(outBuf + pt * S + colOff + pr * 2) = pack2bf(r0, r1);
  }
}

// coalesced warped gather from transposed bf16 feat1 ([HW][C]); uint4-vectorized
__device__ void gather_tile_T(const unsigned short* __restrict__ T,
    const int* offT0, const int* offT1, const float* wxA, const float* wyA,
    unsigned short* outBuf, int colOff)
{
  for (int it = threadIdx.x; it < MP * 16; it += NTH) {
    int pt = it >> 4;
    int c8 = (it & 15) * 8;
    int e0 = offT0[pt], e1 = offT1[pt];
    int du = (e0 & 1) << 7;
    int o00 = e0 & ~1, o10 = e1 & ~1;
    float wx = wxA[pt], wy = wyA[pt];
    uint4 a00 = *(const uint4*)(T + o00 + c8);
    uint4 a01 = *(const uint4*)(T + o00 + du + c8);
    uint4 a10 = *(const uint4*)(T + o10 + c8);
    uint4 a11 = *(const uint4*)(T + o10 + du + c8);
    float w11 = wx * wy;
    float w01 = wx - w11, w10 = wy - w11, w00 = 1.0f - wx - wy + w11;
    uint4 res;
    const unsigned* p00 = (const unsigned*)&a00;
    const unsigned* p01 = (const unsigned*)&a01;
    const unsigned* p10 = (const unsigned*)&a10;
    const unsigned* p11 = (const unsigned*)&a11;
    unsigned* pr = (unsigned*)&res;
#pragma unroll
    for (int q = 0; q < 4; ++q) {
      float r0 = w00 * bflo(p00[q]) + w01 * bflo(p01[q])
               + w10 * bflo(p10[q]) + w11 * bflo(p11[q]);
      float r1 = w00 * bfhi(p00[q]) + w01 * bfhi(p01[q])
               + w10 * bfhi(p10[q]) + w11 * bfhi(p11[q]);
      pr[q] = pack2bf(r0, r1);
    }
    *(uint4*)(outBuf + pt * S + colOff + c8) = res;
  }
}

__global__ __launch_bounds__(256, 4)
void ifd_kernel(Params p)
{
  __shared__ __align__(16) unsigned short buf[MP * S];   // 37888 B
  __shared__ int offT0[MP], offT1[MP];
  __shared__ int pcBoth[MP];
  __shared__ float w8x[MP], w16x[MP], wWx[MP], wWy[MP];
  __shared__ float caxA[MP], cayA[MP];
  __shared__ int uy8_0, uy8_1, uy16_0, uy16_1, ubase8, ubase16;
  __shared__ float uwy8, uwy16;

  float* bufF = (float*)buf;
  bf16x8 pf[4];

  const int blk = blockIdx.x;
  const int bb = blk / (HF * BPR);
  const int r = blk % (HF * BPR);
  const int y = r >> 3;
  const int xb = (r & (BPR - 1)) * MP;
  const int t = threadIdx.x;
  const float lim = 1.0f - 1e-6f;

  if (t < MP) {
    const int i = t;
    const int x = xb + i;
    float gx = (x + 0.5f) * (2.0f / WF) - 1.0f;
    float gy = (y + 0.5f) * (2.0f / HF) - 1.0f;
    gx = fminf(fmaxf(gx, -lim), lim);
    gy = fminf(fmaxf(gy, -lim), lim);

    float gx0 = fminf(fmaxf((xb + 0.5f) * (2.0f / WF) - 1.0f, -lim), lim);
    int base8 = min(max((int)floorf((gx0 + 1.0f) * 32.0f - 0.5f), 0), W8 - 1);
    int base16 = min(max((int)floorf((gx0 + 1.0f) * 16.0f - 0.5f), 0), W16g - 1);

    int x0, x1, y0, y1; float wx, wy;
    bilin_setup(gx, W8, x0, x1, wx);
    bilin_setup(gy, H8, y0, y1, wy);
    w8x[i] = wx;
    int o00 = y0 * W8 + x0, o01 = y0 * W8 + x1;
    int o10 = y1 * W8 + x0, o11 = y1 * W8 + x1;

    int a0, a1, b0i, b1i; float vx, vy;
    bilin_setup(gx, W16g, a0, a1, vx);
    bilin_setup(gy, H16g, b0i, b1i, vy);
    w16x[i] = vx;
    pcBoth[i] = (x0 - base8) | ((x1 - base8) << 4)
              | ((a0 - base16) << 8) | ((a1 - base16) << 12);

    if (i == 0) {
      uy8_0 = y0; uy8_1 = y1; uwy8 = wy;
      uy16_0 = b0i; uy16_1 = b1i; uwy16 = vy;
      ubase8 = base8; ubase16 = base16;
    }

    const float* cf = p.coarse + bb * 2 * HWs8;
    float c00 = cf[o00], c01 = cf[o01], c10 = cf[o10], c11 = cf[o11];
    float cx0 = fmaf(wx, c01 - c00, c00), cx1 = fmaf(wx, c11 - c10, c10);
    float cfx = fmaf(wy, cx1 - cx0, cx0);
    const float* cf2 = cf + HWs8;
    c00 = cf2[o00]; c01 = cf2[o01]; c10 = cf2[o10]; c11 = cf2[o11];
    cx0 = fmaf(wx, c01 - c00, c00); cx1 = fmaf(wx, c11 - c10, c10);
    float cfy = fmaf(wy, cx1 - cx0, cx0);
    float cax = cfx * 8.0f, cay = cfy * 8.0f;
    caxA[i] = cax; cayA[i] = cay;

    float wxn = gx + cax * (2.0f / WF);
    float wyn = gy + cay * (2.0f / HF);
    wxn = fminf(fmaxf(wxn, -lim), lim);
    wyn = fminf(fmaxf(wyn, -lim), lim);
    int u0, u1, v0, v1; float uw, vw;
    bilin_setup(wxn, W8, u0, u1, uw);
    bilin_setup(wyn, H8, v0, v1, vw);
    int du = u1 - u0;
    offT0[i] = ((v0 * W8 + u0) << 7) | du;
    offT1[i] = ((v1 * W8 + u0) << 7) | du;
    wWx[i] = uw; wWy[i] = vw;
  }
  // Wc's A tiles fly during setup/stage/xlerp phases
  prefetchA<1, 2, 4>(p.ws + OFF_WC, pf);
  barrier_lds();

  // stage f8 -> MAP0; ctx -> MAP1
  stage_patch<10, 128, 0>(p.feat_s8 + bb * 128 * HWs8, HWs8, W8,
                          ubase8, uy8_0, uy8_1, uwy8, bufF);
  stage_patch<10, 64, 1>(p.ctx_s8 + bb * 64 * HWs8, HWs8, W8,
                         ubase8, uy8_0, uy8_1, uwy8, bufF);
  barrier_lds();
  xlerp_tile<64, 0, 130>(bufF, pcBoth, 0, w8x, buf, 128);  // f8  -> [128:256)
  xlerp_tile<32, 1, 66>(bufF, pcBoth, 0, w8x, buf, 0);     // ctx -> [0:64)
  barrier_lds();

  // Wc: [0:64) K=64 -> [128:256), residual same cols (A fully prefetched)
  mfma_layer<1, 2, 3, false, 64>(p.ws + OFF_WC, p.bc, buf, buf + 128, p.g1, buf + 128, pf);
  prefetchA<2, 2, 8>(p.ws + OFF_W1, pf);
  // overlap: stage f16 patch -> MAP1
  stage_patch<6, 128, 1>(p.feat_s16 + bb * 128 * HWs16, HWs16, W16g,
                         ubase16, uy16_0, uy16_1, uwy16, bufF);
  barrier_lds();
  // W1: [128:256) K=128 -> [0:256)
  mfma_layer<2, 2, 1, true, 128>(p.ws + OFF_W1, p.b1, buf + 128, buf, nullptr, nullptr, pf);
  prefetchA<1, 2, 16>(p.ws + OFF_W2, pf);
  barrier_lds();
  // W2: [0:256) K=256 -> [0:128); then f16 x-lerp -> [128:256)
  mfma_layer<1, 2, 0, true, 256>(p.ws + OFF_W2, p.b2, buf, buf, nullptr, nullptr, pf);
  xlerp_tile<64, 1, 130>(bufF, pcBoth, 8, w16x, buf, 128);
  prefetchA<1, 2, 8>(p.ws + OFF_WP, pf);
  barrier_lds();
  // Wp: [0:128) -> [128:256), residual same cols
  mfma_layer<1, 2, 3, false, 128>(p.ws + OFF_WP, p.bp, buf, buf + 128, p.g2, buf + 128, pf);
  prefetchA<2, 2, 8>(p.ws + OFF_W3, pf);
  barrier_lds();
  // W3: [128:256) K=128 -> [0:256)
  mfma_layer<2, 2, 1, true, 128>(p.ws + OFF_W3, p.b3, buf + 128, buf, nullptr, nullptr, pf);
  prefetchA<1, 2, 16>(p.ws + OFF_W4, pf);
  barrier_lds();
  // W4: [0:256) K=256 -> [0:128); gather -> [128:256); extras -> [256:272)
  mfma_layer<1, 2, 0, true, 256>(p.ws + OFF_W4, p.b4, buf, buf, nullptr, nullptr, pf);
  gather_tile_T(p.wsT + bb * HWs8 * 128, offT0, offT1, wWx, wWy, buf, 128);
  for (int idx = t; idx < MP * 8; idx += NTH) {
    int row = idx >> 3, c = idx & 7;
    unsigned val = 0;
    if (c == 0) {
      float gx = fminf(fmaxf((xb + row + 0.5f) * (2.0f / WF) - 1.0f, -lim), lim);
      float gy = fminf(fmaxf((y + 0.5f) * (2.0f / HF) - 1.0f, -lim), lim);
      val = pack2bf(gx, gy);
    } else if (c == 1) {
      val = pack2bf(caxA[row] * (1.0f / WF), cayA[row] * (1.0f / HF));
    }
    *(unsigned*)(buf + row * S + 256 + c * 2) = val;
  }
  prefetchA<2, 2, 17>(p.ws + OFF_H0, pf);
  barrier_lds();
  // flow head, all in-place (H0 K padded 260 -> 272)
  mfma_layer<2, 2, 2, true, 272>(p.ws + OFF_H0, p.h0b, buf, buf, nullptr, nullptr, pf);
  prefetchA<1, 2, 16>(p.ws + OFF_H1, pf);
  barrier_lds();
  mfma_layer<1, 2, 2, true, 256>(p.ws + OFF_H1, p.h1b, buf, buf, nullptr, nullptr, pf);
  prefetchA<1, 1, 8>(p.ws + OFF_H2, pf);
  barrier_lds();
  mfma_layer<1, 1, 2, true, 128>(p.ws + OFF_H2, p.h2b, buf, buf, nullptr, nullptr, pf);
  barrier_lds();

  // final 64->2 + output (fp32)
  if (t < 128) {
    int i = t & 63, comp = t >> 6;
    float acc = p.h3b[comp];
    const unsigned short* rowp = buf + i * S;
    const float* wp = p.h3w + comp;
#pragma unroll
    for (int k8 = 0; k8 < 8; ++k8) {
      uint4 av = *(const uint4*)(rowp + k8 * 8);
      const float* w8p = wp + k8 * 16;
      acc = fmaf(bflo(av.x), w8p[0], acc);
      acc = fmaf(bfhi(av.x), w8p[2], acc);
      acc = fmaf(bflo(av.y), w8p[4], acc);
      acc = fmaf(bfhi(av.y), w8p[6], acc);
      acc = fmaf(bflo(av.z), w8p[8], acc);
      acc = fmaf(bfhi(av.z), w8p[10], acc);
      acc = fmaf(bflo(av.w), w8p[12], acc);
      acc = fmaf(bfhi(av.w), w8p[14], acc);
    }
    float flow = (comp ? cayA[i] : caxA[i]) + acc * (comp ? (float)HF : (float)WF);
    p.out[((bb * 2 + comp) * HF + y) * WF + xb + i] = flow;
  }
}

extern "C" void kernel_launch(void* const* d_in, const int* in_sizes, int n_in,
                              void* d_out, int out_size, void* d_ws, size_t ws_size,
                              hipStream_t stream) {
  PrepParams pp;
  pp.W[0] = (const float*)d_in[6];   // Wc
  pp.W[1] = (const float*)d_in[9];   // W1
  pp.W[2] = (const float*)d_in[11];  // W2
  pp.W[3] = (const float*)d_in[13];  // Wp
  pp.W[4] = (const float*)d_in[16];  // W3
  pp.W[5] = (const float*)d_in[18];  // W4
  pp.W[6] = (const float*)d_in[20];  // hw0
  pp.W[7] = (const float*)d_in[22];  // hw1
  pp.W[8] = (const float*)d_in[24];  // hw2
  pp.f1   = (const float*)d_in[2];   // feat1_s8
  pp.ws = (unsigned short*)d_ws;
  hipLaunchKernelGGL(prep_kernel, dim3(PREP_W_BLOCKS + PREP_T_BLOCKS), dim3(NTH),
                     0, stream, pp);

  Params p;
  p.feat_s8  = (const float*)d_in[1];
  p.feat_s16 = (const float*)d_in[3];
  p.ctx_s8   = (const float*)d_in[4];
  p.coarse   = (const float*)d_in[5];
  p.bc  = (const float*)d_in[7];
  p.g1  = (const float*)d_in[8];
  p.b1  = (const float*)d_in[10];
  p.b2  = (const float*)d_in[12];
  p.bp  = (const float*)d_in[14];
  p.g2  = (const float*)d_in[15];
  p.b3  = (const float*)d_in[17];
  p.b4  = (const float*)d_in[19];
  p.h0b = (const float*)d_in[21];
  p.h1b = (const float*)d_in[23];
  p.h2b = (const float*)d_in[25];
  p.h3w = (const float*)d_in[26];
  p.h3b = (const float*)d_in[27];
  p.ws  = (const unsigned short*)d_ws;
  p.wsT = (const unsigned short*)d_ws + OFF_T;
  p.out = (float*)d_out;

  hipLaunchKernelGGL(ifd_kernel, dim3(NBLK), dim3(NTH), 0, stream, p);
}

// Round 3
// 407.245 us; speedup vs baseline: 1.1322x; 1.0260x over previous
//
#include <hip/hip_runtime.h>
#include <math.h>

// ---------------------------------------------------------------------------
// ImplicitFlowDecoder — R12:
//  - ALL feature maps pre-transposed to [HW][C] bf16 in prep (f1, f8, ctx, f16);
//    sampling is now a uniform 4-tap uint4 gather -> deletes stage_patch/xlerp,
//    one barrier, the f32 patch staging (bank-conflict source) and uniform-y
//    machinery.
//  - bias back in accumulator init (R11's epilogue-bias cost +4pp VALUBusy).
//  - S 296->280 (staging dead columns gone).
// R11: lgkm-only barriers + A-fragment prefetch across barriers (kept).
// R10: constexpr prep swizzle, H0 K=272, exp2-folded gelu, s_setprio (kept).
// ---------------------------------------------------------------------------

typedef short bf16x8 __attribute__((ext_vector_type(8)));
typedef float f32x16 __attribute__((ext_vector_type(16)));

constexpr int W8 = 64, H8 = 48, W16g = 32, H16g = 24, WF = 512, HF = 384;
constexpr int HWs8 = W8 * H8;      // 3072
constexpr int HWs16 = W16g * H16g; // 768
constexpr int MP = 64;
constexpr int NTH = 256;
constexpr int BPR = WF / MP;                // 8
constexpr int NBLK = 2 * HF * BPR;          // 6144

constexpr int S = 280;      // row stride (ushorts), 8-aligned for b128
constexpr int SD = S / 2;

// d_ws layout (ushort elems)
constexpr int OFF_WC = 0;
constexpr int OFF_W1 = 8192;
constexpr int OFF_W2 = 40960;
constexpr int OFF_WP = 73728;
constexpr int OFF_W3 = 90112;
constexpr int OFF_W4 = 122880;
constexpr int OFF_H0 = 155648;   // K padded 260->272
constexpr int OFF_H1 = 225280;
constexpr int OFF_H2 = 258048;
constexpr int SWZ_TOTAL = 266240;
// transposed feature maps, bf16 [B][HW][C]
constexpr int OFF_T   = SWZ_TOTAL;                 // feat1   [2][3072][128]
constexpr int OFF_T8  = OFF_T  + 2 * HWs8 * 128;   // feat_s8 [2][3072][128]
constexpr int OFF_TC  = OFF_T8 + 2 * HWs8 * 128;   // ctx     [2][3072][64]
constexpr int OFF_T16 = OFF_TC + 2 * HWs8 * 64;    // feat_s16[2][768][128]

__device__ __forceinline__ unsigned short f2bf(float f) {  // RNE (prep only)
  union { float f; unsigned u; } v; v.f = f;
  unsigned r = (v.u + 0x7fffu + ((v.u >> 16) & 1u)) >> 16;
  return (unsigned short)r;
}
__device__ __forceinline__ float bflo(unsigned u) {
  return __builtin_bit_cast(float, u << 16);
}
__device__ __forceinline__ float bfhi(unsigned u) {
  return __builtin_bit_cast(float, u & 0xffff0000u);
}
#if defined(__has_builtin)
#if __has_builtin(__builtin_amdgcn_cvt_pk_bf16_f32)
#define HAS_PK_BF16 1
#endif
#if __has_builtin(__builtin_amdgcn_exp2f)
#define HAS_EXP2 1
#endif
#endif
__device__ __forceinline__ unsigned pack2bf(float a, float b) {
#ifdef HAS_PK_BF16
  typedef __bf16 bf2_t __attribute__((ext_vector_type(2)));
  bf2_t r = __builtin_amdgcn_cvt_pk_bf16_f32(a, b);
  return __builtin_bit_cast(unsigned, r);
#else
  unsigned ua = __builtin_bit_cast(unsigned, a) + 0x8000u;
  unsigned ub = __builtin_bit_cast(unsigned, b) + 0x8000u;
  return __builtin_amdgcn_perm(ub, ua, 0x07060302u);
#endif
}
__device__ __forceinline__ float exp2_fast(float x) {
#ifdef HAS_EXP2
  return __builtin_amdgcn_exp2f(x);
#else
  float r;
  asm("v_exp_f32 %0, %1" : "=v"(r) : "v"(x));
  return r;
#endif
}
// tanh-GELU in sigmoid form with log2e pre-folded
__device__ __forceinline__ float gelu_fast(float x) {
  float t = fmaf(x * x, -0.10294433f, -2.3022082f);
  float e = exp2_fast(x * t);
  return x * __builtin_amdgcn_rcpf(1.0f + e);
}

// LDS-only barrier: no vmcnt(0) drain (no cross-thread global deps in-kernel).
__device__ __forceinline__ void barrier_lds() {
  asm volatile("s_waitcnt lgkmcnt(0)" ::: "memory");
  __builtin_amdgcn_s_barrier();
  asm volatile("" ::: "memory");
}

// ------------------------------- prep kernel -------------------------------
struct PrepParams {
  const float* W[9];
  const float* f1; const float* f8; const float* ctx; const float* f16;
  unsigned short* ws;
};

constexpr int PTH = 256;
constexpr int PREP_W_BLOCKS = SWZ_TOTAL / PTH;   // 1040
constexpr int HWT = 32;                          // hw tile for transpose
// transpose blocks: f1 192, f8 192, ctx 192, f16 48
constexpr int TB_F1 = 2 * (HWs8 / HWT);
constexpr int TB_F8 = TB_F1;
constexpr int TB_CTX = TB_F1;
constexpr int TB_F16 = 2 * (HWs16 / HWT);
constexpr int PREP_T_BLOCKS = TB_F1 + TB_F8 + TB_CTX + TB_F16;  // 624

template<int KK, int KP, int NN>
__device__ __forceinline__ void prep_one(const float* __restrict__ W,
                                         unsigned short* __restrict__ dst, int q) {
  int j = q & 7;
  int l = (q >> 3) & 63;
  int r = q >> 9;
  constexpr int nks = KP >> 4;
  int ks = r % nks;
  int mt = r / nks;
  int n = mt * 32 + (l & 31);
  int k = ks * 16 + ((l >> 5) << 3) + j;
  float v = (k < KK) ? W[k * NN + n] : 0.0f;
  dst[q] = f2bf(v);
}

// [C][HWtot] f32 -> [HWtot][C] bf16, both sides coalesced, one HWT-column tile
template<int C>
__device__ __forceinline__ void transpose_fm(const float* __restrict__ src,
    unsigned short* __restrict__ dst, int HWtot, int hw0,
    unsigned short* __restrict__ tile)
{
  const int t = threadIdx.x;
  const int hw = t & (HWT - 1);
  const int cg = t >> 5;               // 0..7
#pragma unroll
  for (int c0 = 0; c0 < C / 8; ++c0) {
    int c = c0 * 8 + cg;
    tile[c * (HWT + 2) + hw] = f2bf(src[(size_t)c * HWtot + hw0 + hw]);
  }
  __syncthreads();
  constexpr int CD = C / 2;            // dwords per dst row
  constexpr int RP = 256 / CD;         // rows per pass
  const int cD = t & (CD - 1);
  const int hg = t / CD;
#pragma unroll
  for (int h0 = 0; h0 < HWT / RP; ++h0) {
    int hh = h0 * RP + hg;
    unsigned lo = tile[(2 * cD) * (HWT + 2) + hh];
    unsigned hi = tile[(2 * cD + 1) * (HWT + 2) + hh];
    *(unsigned*)(dst + (size_t)(hw0 + hh) * C + 2 * cD) = lo | (hi << 16);
  }
}

__global__ void prep_kernel(PrepParams pp) {
  __shared__ unsigned short tile[128 * (HWT + 2)];   // 8704 B
  const int blk = blockIdx.x;
  if (blk < PREP_W_BLOCKS) {
    int e = blk * PTH + threadIdx.x;
    unsigned short* ws = pp.ws;
    if (e < OFF_W1)      prep_one<64, 64, 128>(pp.W[0], ws + OFF_WC, e - OFF_WC);
    else if (e < OFF_W2) prep_one<128, 128, 256>(pp.W[1], ws + OFF_W1, e - OFF_W1);
    else if (e < OFF_WP) prep_one<256, 256, 128>(pp.W[2], ws + OFF_W2, e - OFF_W2);
    else if (e < OFF_W3) prep_one<128, 128, 128>(pp.W[3], ws + OFF_WP, e - OFF_WP);
    else if (e < OFF_W4) prep_one<128, 128, 256>(pp.W[4], ws + OFF_W3, e - OFF_W3);
    else if (e < OFF_H0) prep_one<256, 256, 128>(pp.W[5], ws + OFF_W4, e - OFF_W4);
    else if (e < OFF_H1) prep_one<260, 272, 256>(pp.W[6], ws + OFF_H0, e - OFF_H0);
    else if (e < OFF_H2) prep_one<256, 256, 128>(pp.W[7], ws + OFF_H1, e - OFF_H1);
    else                 prep_one<128, 128, 64>(pp.W[8], ws + OFF_H2, e - OFF_H2);
  } else {
    int tb = blk - PREP_W_BLOCKS;
    if (tb < TB_F1) {
      int b = tb / (HWs8 / HWT), hw0 = (tb % (HWs8 / HWT)) * HWT;
      transpose_fm<128>(pp.f1 + (size_t)b * 128 * HWs8,
                        pp.ws + OFF_T + (size_t)b * HWs8 * 128, HWs8, hw0, tile);
    } else if (tb < TB_F1 + TB_F8) {
      tb -= TB_F1;
      int b = tb / (HWs8 / HWT), hw0 = (tb % (HWs8 / HWT)) * HWT;
      transpose_fm<128>(pp.f8 + (size_t)b * 128 * HWs8,
                        pp.ws + OFF_T8 + (size_t)b * HWs8 * 128, HWs8, hw0, tile);
    } else if (tb < TB_F1 + TB_F8 + TB_CTX) {
      tb -= TB_F1 + TB_F8;
      int b = tb / (HWs8 / HWT), hw0 = (tb % (HWs8 / HWT)) * HWT;
      transpose_fm<64>(pp.ctx + (size_t)b * 64 * HWs8,
                       pp.ws + OFF_TC + (size_t)b * HWs8 * 64, HWs8, hw0, tile);
    } else {
      tb -= TB_F1 + TB_F8 + TB_CTX;
      int b = tb / (HWs16 / HWT), hw0 = (tb % (HWs16 / HWT)) * HWT;
      transpose_fm<128>(pp.f16 + (size_t)b * 128 * HWs16,
                        pp.ws + OFF_T16 + (size_t)b * HWs16 * 128, HWs16, hw0, tile);
    }
  }
}

// ------------------------------ main kernel --------------------------------
struct Params {
  const float* coarse;
  const float* bc; const float* g1; const float* b1; const float* b2;
  const float* bp; const float* g2; const float* b3; const float* b4;
  const float* h0b; const float* h1b; const float* h2b;
  const float* h3w; const float* h3b;
  const unsigned short* ws;
  const unsigned short* wsT;   // feat1 T
  const unsigned short* wsT8;  // feat_s8 T
  const unsigned short* wsTC;  // ctx T
  const unsigned short* wsT16; // feat_s16 T
  float* out;
};

__device__ __forceinline__ void bilin_setup(float g, int Sg, int& i0, int& i1, float& w) {
  float s = (g + 1.0f) * (0.5f * Sg) - 0.5f;
  float f = floorf(s);
  w = s - f;
  int a = (int)f;
  i0 = min(max(a, 0), Sg - 1);
  i1 = min(max(a + 1, 0), Sg - 1);
}

// prefetch the next layer's first 4 A tiles (consumption order: ks-major, m-minor)
template<int MTN, int NTN, int NKSN>
__device__ __forceinline__ void prefetchA(const unsigned short* __restrict__ Wsw,
                                          bf16x8* pf) {
  const int t = threadIdx.x;
  const int l = t & 63;
  const int wv = t >> 6;
  const int mt0 = (NTN == 2) ? wv * MTN : (wv >> 1);
  const unsigned short* ab = Wsw + (size_t)mt0 * NKSN * 512 + l * 8;
  if (MTN == 1) {
#pragma unroll
    for (int i = 0; i < 4; ++i) pf[i] = *(const bf16x8*)(ab + i * 512);
  } else {
    pf[0] = *(const bf16x8*)(ab);
    pf[1] = *(const bf16x8*)(ab + (size_t)NKSN * 512);
    pf[2] = *(const bf16x8*)(ab + 512);
    pf[3] = *(const bf16x8*)(ab + (size_t)NKSN * 512 + 512);
  }
}

// 32x32x16 MFMA layer; bias in accumulator init; first 4 A tiles from pf.
template<int MT, int NT, int EP, bool SYNC, int K>
__device__ __forceinline__ void mfma_layer(
    const unsigned short* __restrict__ Wsw,
    const float* __restrict__ bias,
    const unsigned short* actIn,
    unsigned short* actOut,
    const float* __restrict__ gate,
    const unsigned short* res,
    const bf16x8* pf)
{
  const int t = threadIdx.x;
  const int l = t & 63;
  const int wv = t >> 6;
  constexpr int nks = K >> 4;
  const int mt0 = (NT == 2) ? wv * MT : (wv >> 1);
  const int ntb = (NT == 2) ? 0 : (wv & 1);
  const int lh = l >> 5;
  const int ll = l & 31;

  f32x16 acc[MT][NT];
#pragma unroll
  for (int m = 0; m < MT; ++m) {
#pragma unroll
    for (int g = 0; g < 4; ++g) {
      const int f0 = (mt0 + m) * 32 + g * 8 + (lh << 2);
      const float4 bv = *(const float4*)(bias + f0);
#pragma unroll
      for (int nt = 0; nt < NT; ++nt) {
        acc[m][nt][g * 4 + 0] = bv.x; acc[m][nt][g * 4 + 1] = bv.y;
        acc[m][nt][g * 4 + 2] = bv.z; acc[m][nt][g * 4 + 3] = bv.w;
      }
    }
  }

  const unsigned short* bbase = actIn + (ntb * 32 + ll) * S + (lh << 3);
  const unsigned short* abase = Wsw + (size_t)mt0 * nks * 512 + l * 8;

  __builtin_amdgcn_s_setprio(1);
#pragma unroll
  for (int ks = 0; ks < nks; ++ks) {
    bf16x8 B[NT];
#pragma unroll
    for (int nt = 0; nt < NT; ++nt)
      B[nt] = *(const bf16x8*)(bbase + nt * 32 * S + ks * 16);
#pragma unroll
    for (int m = 0; m < MT; ++m) {
      bf16x8 A;
      if (ks * MT + m < 4) A = pf[ks * MT + m];
      else A = *(const bf16x8*)(abase + (m * nks + ks) * 512);
#pragma unroll
      for (int nt = 0; nt < NT; ++nt)
        acc[m][nt] = __builtin_amdgcn_mfma_f32_32x32x16_bf16(A, B[nt], acc[m][nt], 0, 0, 0);
    }
  }
  __builtin_amdgcn_s_setprio(0);

  if (SYNC) barrier_lds();

#pragma unroll
  for (int m = 0; m < MT; ++m) {
#pragma unroll
    for (int g = 0; g < 4; ++g) {
      const int f0 = (mt0 + m) * 32 + g * 8 + (lh << 2);
      float4 gv;
      if (EP == 3) {
        float4 gg = *(const float4*)(gate + f0);
        gv.x = __builtin_amdgcn_rcpf(1.0f + exp2_fast(gg.x * -1.44269504f));
        gv.y = __builtin_amdgcn_rcpf(1.0f + exp2_fast(gg.y * -1.44269504f));
        gv.z = __builtin_amdgcn_rcpf(1.0f + exp2_fast(gg.z * -1.44269504f));
        gv.w = __builtin_amdgcn_rcpf(1.0f + exp2_fast(gg.w * -1.44269504f));
      }
#pragma unroll
      for (int nt = 0; nt < NT; ++nt) {
        const int pt = (ntb + nt) * 32 + ll;
        float v[4];
        v[0] = acc[m][nt][g * 4 + 0]; v[1] = acc[m][nt][g * 4 + 1];
        v[2] = acc[m][nt][g * 4 + 2]; v[3] = acc[m][nt][g * 4 + 3];
        if (EP == 1) {
#pragma unroll
          for (int r = 0; r < 4; ++r) v[r] = gelu_fast(v[r]);
        } else if (EP == 2) {
#pragma unroll
          for (int r = 0; r < 4; ++r) v[r] = fmaxf(v[r], 0.0f);
        } else if (EP == 3) {
          uint2 rv = *(const uint2*)(res + pt * S + f0);
          v[0] = fmaf(gv.x, v[0], bflo(rv.x));
          v[1] = fmaf(gv.y, v[1], bfhi(rv.x));
          v[2] = fmaf(gv.z, v[2], bflo(rv.y));
          v[3] = fmaf(gv.w, v[3], bfhi(rv.y));
        }
        uint2 pk;
        pk.x = pack2bf(v[0], v[1]);
        pk.y = pack2bf(v[2], v[3]);
        *(uint2*)(actOut + pt * S + f0) = pk;
      }
    }
  }
}

// 4-tap bilinear gather from transposed bf16 [HW][CH] map; 8 channels per item
template<int CH>
__device__ void gather_bilin(const unsigned short* __restrict__ T,
    const int* offA, const int* offB, const float* wxA, const float* wyA,
    unsigned short* outBuf, int colOff)
{
  constexpr int IPP = CH / 8;   // items per point (16 or 8)
  for (int it = threadIdx.x; it < MP * IPP; it += NTH) {
    int pt = it / IPP;
    int c8 = (it & (IPP - 1)) * 8;
    int e0 = offA[pt], e1 = offB[pt];
    int du = (e0 & 1) * CH;
    int o0 = (e0 >> 1) * CH + c8;
    int o1 = (e1 >> 1) * CH + c8;
    float wx = wxA[pt], wy = wyA[pt];
    uint4 a00 = *(const uint4*)(T + o0);
    uint4 a01 = *(const uint4*)(T + o0 + du);
    uint4 a10 = *(const uint4*)(T + o1);
    uint4 a11 = *(const uint4*)(T + o1 + du);
    float w11 = wx * wy;
    float w01 = wx - w11, w10 = wy - w11, w00 = 1.0f - wx - wy + w11;
    uint4 res;
    const unsigned* p00 = (const unsigned*)&a00;
    const unsigned* p01 = (const unsigned*)&a01;
    const unsigned* p10 = (const unsigned*)&a10;
    const unsigned* p11 = (const unsigned*)&a11;
    unsigned* pr = (unsigned*)&res;
#pragma unroll
    for (int q = 0; q < 4; ++q) {
      float r0 = w00 * bflo(p00[q]) + w01 * bflo(p01[q])
               + w10 * bflo(p10[q]) + w11 * bflo(p11[q]);
      float r1 = w00 * bfhi(p00[q]) + w01 * bfhi(p01[q])
               + w10 * bfhi(p10[q]) + w11 * bfhi(p11[q]);
      pr[q] = pack2bf(r0, r1);
    }
    *(uint4*)(outBuf + pt * S + colOff + c8) = res;   // 16B aligned (S*2=560)
  }
}

__global__ __launch_bounds__(256, 4)
void ifd_kernel(Params p)
{
  __shared__ __align__(16) unsigned short buf[MP * S];   // 35840 B
  __shared__ int off8_0[MP], off8_1[MP];                  // s8 grid (f8 + ctx)
  __shared__ int of16_0[MP], of16_1[MP];                  // s16 grid
  __shared__ int offT0[MP], offT1[MP];                    // warped (f1)
  __shared__ float w8x[MP], w8y[MP], w16x[MP], w16y[MP], wWx[MP], wWy[MP];
  __shared__ float caxA[MP], cayA[MP];

  bf16x8 pf[4];

  const int blk = blockIdx.x;
  const int bb = blk / (HF * BPR);
  const int r = blk % (HF * BPR);
  const int y = r >> 3;
  const int xb = (r & (BPR - 1)) * MP;
  const int t = threadIdx.x;
  const float lim = 1.0f - 1e-6f;

  if (t < MP) {
    const int i = t;
    const int x = xb + i;
    float gx = (x + 0.5f) * (2.0f / WF) - 1.0f;
    float gy = (y + 0.5f) * (2.0f / HF) - 1.0f;
    gx = fminf(fmaxf(gx, -lim), lim);
    gy = fminf(fmaxf(gy, -lim), lim);

    int x0, x1, y0, y1; float wx, wy;
    bilin_setup(gx, W8, x0, x1, wx);
    bilin_setup(gy, H8, y0, y1, wy);
    w8x[i] = wx; w8y[i] = wy;
    int du8 = x1 - x0;
    off8_0[i] = ((y0 * W8 + x0) << 1) | du8;
    off8_1[i] = ((y1 * W8 + x0) << 1) | du8;

    int a0, a1, b0i, b1i; float vx, vy;
    bilin_setup(gx, W16g, a0, a1, vx);
    bilin_setup(gy, H16g, b0i, b1i, vy);
    w16x[i] = vx; w16y[i] = vy;
    int du16 = a1 - a0;
    of16_0[i] = ((b0i * W16g + a0) << 1) | du16;
    of16_1[i] = ((b1i * W16g + a0) << 1) | du16;

    int o00 = y0 * W8 + x0, o01 = y0 * W8 + x1;
    int o10 = y1 * W8 + x0, o11 = y1 * W8 + x1;
    const float* cf = p.coarse + bb * 2 * HWs8;
    float c00 = cf[o00], c01 = cf[o01], c10 = cf[o10], c11 = cf[o11];
    float cx0 = fmaf(wx, c01 - c00, c00), cx1 = fmaf(wx, c11 - c10, c10);
    float cfx = fmaf(wy, cx1 - cx0, cx0);
    const float* cf2 = cf + HWs8;
    c00 = cf2[o00]; c01 = cf2[o01]; c10 = cf2[o10]; c11 = cf2[o11];
    cx0 = fmaf(wx, c01 - c00, c00); cx1 = fmaf(wx, c11 - c10, c10);
    float cfy = fmaf(wy, cx1 - cx0, cx0);
    float cax = cfx * 8.0f, cay = cfy * 8.0f;
    caxA[i] = cax; cayA[i] = cay;

    float wxn = gx + cax * (2.0f / WF);
    float wyn = gy + cay * (2.0f / HF);
    wxn = fminf(fmaxf(wxn, -lim), lim);
    wyn = fminf(fmaxf(wyn, -lim), lim);
    int u0, u1, v0, v1; float uw, vw;
    bilin_setup(wxn, W8, u0, u1, uw);
    bilin_setup(wyn, H8, v0, v1, vw);
    int duW = u1 - u0;
    offT0[i] = ((v0 * W8 + u0) << 1) | duW;
    offT1[i] = ((v1 * W8 + u0) << 1) | duW;
    wWx[i] = uw; wWy[i] = vw;
  }
  // Wc's A tiles fly during setup/gather phases
  prefetchA<1, 2, 4>(p.ws + OFF_WC, pf);
  barrier_lds();

  // direct gathers: f8 -> [128:256), ctx -> [0:64)   (share s8 offsets)
  gather_bilin<128>(p.wsT8 + (size_t)bb * HWs8 * 128, off8_0, off8_1, w8x, w8y, buf, 128);
  gather_bilin<64>(p.wsTC + (size_t)bb * HWs8 * 64, off8_0, off8_1, w8x, w8y, buf, 0);
  barrier_lds();

  // Wc: [0:64) K=64 -> [128:256), residual same cols (A fully prefetched)
  mfma_layer<1, 2, 3, false, 64>(p.ws + OFF_WC, p.bc, buf, buf + 128, p.g1, buf + 128, pf);
  prefetchA<2, 2, 8>(p.ws + OFF_W1, pf);
  barrier_lds();
  // W1: [128:256) K=128 -> [0:256)
  mfma_layer<2, 2, 1, true, 128>(p.ws + OFF_W1, p.b1, buf + 128, buf, nullptr, nullptr, pf);
  prefetchA<1, 2, 16>(p.ws + OFF_W2, pf);
  barrier_lds();
  // W2: [0:256) K=256 -> [0:128); then f16 gather -> [128:256)
  mfma_layer<1, 2, 0, true, 256>(p.ws + OFF_W2, p.b2, buf, buf, nullptr, nullptr, pf);
  gather_bilin<128>(p.wsT16 + (size_t)bb * HWs16 * 128, of16_0, of16_1, w16x, w16y, buf, 128);
  prefetchA<1, 2, 8>(p.ws + OFF_WP, pf);
  barrier_lds();
  // Wp: [0:128) -> [128:256), residual same cols
  mfma_layer<1, 2, 3, false, 128>(p.ws + OFF_WP, p.bp, buf, buf + 128, p.g2, buf + 128, pf);
  prefetchA<2, 2, 8>(p.ws + OFF_W3, pf);
  barrier_lds();
  // W3: [128:256) K=128 -> [0:256)
  mfma_layer<2, 2, 1, true, 128>(p.ws + OFF_W3, p.b3, buf + 128, buf, nullptr, nullptr, pf);
  prefetchA<1, 2, 16>(p.ws + OFF_W4, pf);
  barrier_lds();
  // W4: [0:256) K=256 -> [0:128); f1 gather -> [128:256); extras -> [256:272)
  mfma_layer<1, 2, 0, true, 256>(p.ws + OFF_W4, p.b4, buf, buf, nullptr, nullptr, pf);
  gather_bilin<128>(p.wsT + (size_t)bb * HWs8 * 128, offT0, offT1, wWx, wWy, buf, 128);
  for (int idx = t; idx < MP * 8; idx += NTH) {
    int row = idx >> 3, c = idx & 7;
    unsigned val = 0;
    if (c == 0) {
      float gx = fminf(fmaxf((xb + row + 0.5f) * (2.0f / WF) - 1.0f, -lim), lim);
      float gy = fminf(fmaxf((y + 0.5f) * (2.0f / HF) - 1.0f, -lim), lim);
      val = pack2bf(gx, gy);
    } else if (c == 1) {
      val = pack2bf(caxA[row] * (1.0f / WF), cayA[row] * (1.0f / HF));
    }
    *(unsigned*)(buf + row * S + 256 + c * 2) = val;
  }
  prefetchA<2, 2, 17>(p.ws + OFF_H0, pf);
  barrier_lds();
  // flow head, all in-place (H0 K padded 260 -> 272)
  mfma_layer<2, 2, 2, true, 272>(p.ws + OFF_H0, p.h0b, buf, buf, nullptr, nullptr, pf);
  prefetchA<1, 2, 16>(p.ws + OFF_H1, pf);
  barrier_lds();
  mfma_layer<1, 2, 2, true, 256>(p.ws + OFF_H1, p.h1b, buf, buf, nullptr, nullptr, pf);
  prefetchA<1, 1, 8>(p.ws + OFF_H2, pf);
  barrier_lds();
  mfma_layer<1, 1, 2, true, 128>(p.ws + OFF_H2, p.h2b, buf, buf, nullptr, nullptr, pf);
  barrier_lds();

  // final 64->2 + output (fp32)
  if (t < 128) {
    int i = t & 63, comp = t >> 6;
    float acc = p.h3b[comp];
    const unsigned short* rowp = buf + i * S;
    const float* wp = p.h3w + comp;
#pragma unroll
    for (int k8 = 0; k8 < 8; ++k8) {
      uint4 av = *(const uint4*)(rowp + k8 * 8);
      const float* w8p = wp + k8 * 16;
      acc = fmaf(bflo(av.x), w8p[0], acc);
      acc = fmaf(bfhi(av.x), w8p[2], acc);
      acc = fmaf(bflo(av.y), w8p[4], acc);
      acc = fmaf(bfhi(av.y), w8p[6], acc);
      acc = fmaf(bflo(av.z), w8p[8], acc);
      acc = fmaf(bfhi(av.z), w8p[10], acc);
      acc = fmaf(bflo(av.w), w8p[12], acc);
      acc = fmaf(bfhi(av.w), w8p[14], acc);
    }
    float flow = (comp ? cayA[i] : caxA[i]) + acc * (comp ? (float)HF : (float)WF);
    p.out[((bb * 2 + comp) * HF + y) * WF + xb + i] = flow;
  }
}

extern "C" void kernel_launch(void* const* d_in, const int* in_sizes, int n_in,
                              void* d_out, int out_size, void* d_ws, size_t ws_size,
                              hipStream_t stream) {
  PrepParams pp;
  pp.W[0] = (const float*)d_in[6];   // Wc
  pp.W[1] = (const float*)d_in[9];   // W1
  pp.W[2] = (const float*)d_in[11];  // W2
  pp.W[3] = (const float*)d_in[13];  // Wp
  pp.W[4] = (const float*)d_in[16];  // W3
  pp.W[5] = (const float*)d_in[18];  // W4
  pp.W[6] = (const float*)d_in[20];  // hw0
  pp.W[7] = (const float*)d_in[22];  // hw1
  pp.W[8] = (const float*)d_in[24];  // hw2
  pp.f1   = (const float*)d_in[2];   // feat1_s8
  pp.f8   = (const float*)d_in[1];   // feat_s8
  pp.ctx  = (const float*)d_in[4];   // ctx_s8
  pp.f16  = (const float*)d_in[3];   // feat_s16
  pp.ws = (unsigned short*)d_ws;
  hipLaunchKernelGGL(prep_kernel, dim3(PREP_W_BLOCKS + PREP_T_BLOCKS), dim3(PTH),
                     0, stream, pp);

  Params p;
  p.coarse = (const float*)d_in[5];
  p.bc  = (const float*)d_in[7];
  p.g1  = (const float*)d_in[8];
  p.b1  = (const float*)d_in[10];
  p.b2  = (const float*)d_in[12];
  p.bp  = (const float*)d_in[14];
  p.g2  = (const float*)d_in[15];
  p.b3  = (const float*)d_in[17];
  p.b4  = (const float*)d_in[19];
  p.h0b = (const float*)d_in[21];
  p.h1b = (const float*)d_in[23];
  p.h2b = (const float*)d_in[25];
  p.h3w = (const float*)d_in[26];
  p.h3b = (const float*)d_in[27];
  p.ws   = (const unsigned short*)d_ws;
  p.wsT  = (const unsigned short*)d_ws + OFF_T;
  p.wsT8 = (const unsigned short*)d_ws + OFF_T8;
  p.wsTC = (const unsigned short*)d_ws + OFF_TC;
  p.wsT16= (const unsigned short*)d_ws + OFF_T16;
  p.out = (float*)d_out;

  hipLaunchKernelGGL(ifd_kernel, dim3(NBLK), dim3(NTH), 0, stream, p);
}

// Round 4
// 401.071 us; speedup vs baseline: 1.1496x; 1.0154x over previous
//
#include <hip/hip_runtime.h>
#include <math.h>

// ---------------------------------------------------------------------------
// ImplicitFlowDecoder — R13:
//  - ALGEBRAIC FUSION: W2 (256->128) and Wp (128->128) have no nonlinearity
//    between them -> fused WF = W2@Wp, bF = b2@Wp + bp, computed fp32 in prep.
//    Deletes one layer: -16 MFMA/wave, -2 barriers, -32 outputs/lane epilogue.
//  - fused layer's f16 residual done as per-lane in-register 4-tap gather in
//    the epilogue (EP5) — no LDS round-trip, no extra barrier.
//  - sigmoid(gate1/2) precomputed to f32 tables in prep (EP3/EP5 load direct).
// R12: all feature maps pre-transposed [HW][C] bf16; uniform uint4 gathers.
// R11: lgkm-only barriers + A-prefetch across barriers. R10: constexpr prep,
//      H0 K=272, exp2 gelu, s_setprio.
// ---------------------------------------------------------------------------

typedef short bf16x8 __attribute__((ext_vector_type(8)));
typedef float f32x16 __attribute__((ext_vector_type(16)));

constexpr int W8 = 64, H8 = 48, W16g = 32, H16g = 24, WF_ = 512, HF = 384;
constexpr int HWs8 = W8 * H8;      // 3072
constexpr int HWs16 = W16g * H16g; // 768
constexpr int MP = 64;
constexpr int NTH = 256;
constexpr int BPR = WF_ / MP;               // 8
constexpr int NBLK = 2 * HF * BPR;          // 6144

constexpr int S = 280;      // row stride (ushorts), 8-aligned for b128

// d_ws layout (ushort elems)
constexpr int OFF_WC = 0;
constexpr int OFF_W1 = 8192;
constexpr int OFF_W2 = 40960;    // now holds fused WF (256x128)
constexpr int OFF_WP = 73728;    // unused region (kept for layout stability)
constexpr int OFF_W3 = 90112;
constexpr int OFF_W4 = 122880;
constexpr int OFF_H0 = 155648;   // K padded 260->272
constexpr int OFF_H1 = 225280;
constexpr int OFF_H2 = 258048;
constexpr int SWZ_TOTAL = 266240;
// transposed feature maps, bf16 [B][HW][C]
constexpr int OFF_T   = SWZ_TOTAL;                 // feat1   [2][3072][128]
constexpr int OFF_T8  = OFF_T  + 2 * HWs8 * 128;   // feat_s8 [2][3072][128]
constexpr int OFF_TC  = OFF_T8 + 2 * HWs8 * 128;   // ctx     [2][3072][64]
constexpr int OFF_T16 = OFF_TC + 2 * HWs8 * 64;    // feat_s16[2][768][128]
// small f32 tables (stored in ush units; each 128 floats = 256 ush)
constexpr int OFF_BF  = OFF_T16 + 2 * HWs16 * 128;
constexpr int OFF_G1S = OFF_BF + 256;
constexpr int OFF_G2S = OFF_G1S + 256;

__device__ __forceinline__ unsigned short f2bf(float f) {  // RNE (prep only)
  union { float f; unsigned u; } v; v.f = f;
  unsigned r = (v.u + 0x7fffu + ((v.u >> 16) & 1u)) >> 16;
  return (unsigned short)r;
}
__device__ __forceinline__ float bflo(unsigned u) {
  return __builtin_bit_cast(float, u << 16);
}
__device__ __forceinline__ float bfhi(unsigned u) {
  return __builtin_bit_cast(float, u & 0xffff0000u);
}
#if defined(__has_builtin)
#if __has_builtin(__builtin_amdgcn_cvt_pk_bf16_f32)
#define HAS_PK_BF16 1
#endif
#if __has_builtin(__builtin_amdgcn_exp2f)
#define HAS_EXP2 1
#endif
#endif
__device__ __forceinline__ unsigned pack2bf(float a, float b) {
#ifdef HAS_PK_BF16
  typedef __bf16 bf2_t __attribute__((ext_vector_type(2)));
  bf2_t r = __builtin_amdgcn_cvt_pk_bf16_f32(a, b);
  return __builtin_bit_cast(unsigned, r);
#else
  unsigned ua = __builtin_bit_cast(unsigned, a) + 0x8000u;
  unsigned ub = __builtin_bit_cast(unsigned, b) + 0x8000u;
  return __builtin_amdgcn_perm(ub, ua, 0x07060302u);
#endif
}
__device__ __forceinline__ float exp2_fast(float x) {
#ifdef HAS_EXP2
  return __builtin_amdgcn_exp2f(x);
#else
  float r;
  asm("v_exp_f32 %0, %1" : "=v"(r) : "v"(x));
  return r;
#endif
}
// tanh-GELU in sigmoid form with log2e pre-folded
__device__ __forceinline__ float gelu_fast(float x) {
  float t = fmaf(x * x, -0.10294433f, -2.3022082f);
  float e = exp2_fast(x * t);
  return x * __builtin_amdgcn_rcpf(1.0f + e);
}

// LDS-only barrier: no vmcnt(0) drain (no cross-thread global deps in-kernel).
__device__ __forceinline__ void barrier_lds() {
  asm volatile("s_waitcnt lgkmcnt(0)" ::: "memory");
  __builtin_amdgcn_s_barrier();
  asm volatile("" ::: "memory");
}

// ------------------------------- prep kernel -------------------------------
struct PrepParams {
  const float* W[9];
  const float* f1; const float* f8; const float* ctx; const float* f16;
  const float* b2; const float* bp; const float* g1; const float* g2;
  unsigned short* ws;
};

constexpr int PTH = 256;
constexpr int PREP_W_BLOCKS = SWZ_TOTAL / PTH;   // 1040
constexpr int HWT = 32;
constexpr int TB_F1 = 2 * (HWs8 / HWT);
constexpr int TB_F8 = TB_F1;
constexpr int TB_CTX = TB_F1;
constexpr int TB_F16 = 2 * (HWs16 / HWT);
constexpr int PREP_T_BLOCKS = TB_F1 + TB_F8 + TB_CTX + TB_F16;  // 624

template<int KK, int KP, int NN>
__device__ __forceinline__ void prep_one(const float* __restrict__ W,
                                         unsigned short* __restrict__ dst, int q) {
  int j = q & 7;
  int l = (q >> 3) & 63;
  int r = q >> 9;
  constexpr int nks = KP >> 4;
  int ks = r % nks;
  int mt = r / nks;
  int n = mt * 32 + (l & 31);
  int k = ks * 16 + ((l >> 5) << 3) + j;
  float v = (k < KK) ? W[k * NN + n] : 0.0f;
  dst[q] = f2bf(v);
}

// fused WF[k][n] = sum_j W2[k][j] * Wp[j][n]   (K=256, N=128), fp32 accumulate
__device__ __forceinline__ void prep_fused(const float* __restrict__ W2,
                                           const float* __restrict__ Wp,
                                           unsigned short* __restrict__ dst, int q) {
  int j = q & 7;
  int l = (q >> 3) & 63;
  int r = q >> 9;
  constexpr int nks = 16;
  int ks = r % nks;
  int mt = r / nks;
  int n = mt * 32 + (l & 31);
  int k = ks * 16 + ((l >> 5) << 3) + j;
  float v = 0.0f;
  for (int jj = 0; jj < 128; ++jj)
    v = fmaf(W2[k * 128 + jj], Wp[jj * 128 + n], v);
  dst[q] = f2bf(v);
}

template<int C>
__device__ __forceinline__ void transpose_fm(const float* __restrict__ src,
    unsigned short* __restrict__ dst, int HWtot, int hw0,
    unsigned short* __restrict__ tile)
{
  const int t = threadIdx.x;
  const int hw = t & (HWT - 1);
  const int cg = t >> 5;
#pragma unroll
  for (int c0 = 0; c0 < C / 8; ++c0) {
    int c = c0 * 8 + cg;
    tile[c * (HWT + 2) + hw] = f2bf(src[(size_t)c * HWtot + hw0 + hw]);
  }
  __syncthreads();
  constexpr int CD = C / 2;
  constexpr int RP = 256 / CD;
  const int cD = t & (CD - 1);
  const int hg = t / CD;
#pragma unroll
  for (int h0 = 0; h0 < HWT / RP; ++h0) {
    int hh = h0 * RP + hg;
    unsigned lo = tile[(2 * cD) * (HWT + 2) + hh];
    unsigned hi = tile[(2 * cD + 1) * (HWT + 2) + hh];
    *(unsigned*)(dst + (size_t)(hw0 + hh) * C + 2 * cD) = lo | (hi << 16);
  }
}

__global__ void prep_kernel(PrepParams pp) {
  __shared__ unsigned short tile[128 * (HWT + 2)];
  const int blk = blockIdx.x;
  if (blk < PREP_W_BLOCKS) {
    int e = blk * PTH + threadIdx.x;
    unsigned short* ws = pp.ws;
    if (e < OFF_W1)      prep_one<64, 64, 128>(pp.W[0], ws + OFF_WC, e - OFF_WC);
    else if (e < OFF_W2) prep_one<128, 128, 256>(pp.W[1], ws + OFF_W1, e - OFF_W1);
    else if (e < OFF_WP) prep_fused(pp.W[2], pp.W[3], ws + OFF_W2, e - OFF_W2);
    else if (e < OFF_W3) { /* old Wp region unused */ }
    else if (e < OFF_W4) prep_one<128, 128, 256>(pp.W[4], ws + OFF_W3, e - OFF_W3);
    else if (e < OFF_H0) prep_one<256, 256, 128>(pp.W[5], ws + OFF_W4, e - OFF_W4);
    else if (e < OFF_H1) prep_one<260, 272, 256>(pp.W[6], ws + OFF_H0, e - OFF_H0);
    else if (e < OFF_H2) prep_one<256, 256, 128>(pp.W[7], ws + OFF_H1, e - OFF_H1);
    else                 prep_one<128, 128, 64>(pp.W[8], ws + OFF_H2, e - OFF_H2);
  } else if (blk < PREP_W_BLOCKS + PREP_T_BLOCKS) {
    int tb = blk - PREP_W_BLOCKS;
    if (tb < TB_F1) {
      int b = tb / (HWs8 / HWT), hw0 = (tb % (HWs8 / HWT)) * HWT;
      transpose_fm<128>(pp.f1 + (size_t)b * 128 * HWs8,
                        pp.ws + OFF_T + (size_t)b * HWs8 * 128, HWs8, hw0, tile);
    } else if (tb < TB_F1 + TB_F8) {
      tb -= TB_F1;
      int b = tb / (HWs8 / HWT), hw0 = (tb % (HWs8 / HWT)) * HWT;
      transpose_fm<128>(pp.f8 + (size_t)b * 128 * HWs8,
                        pp.ws + OFF_T8 + (size_t)b * HWs8 * 128, HWs8, hw0, tile);
    } else if (tb < TB_F1 + TB_F8 + TB_CTX) {
      tb -= TB_F1 + TB_F8;
      int b = tb / (HWs8 / HWT), hw0 = (tb % (HWs8 / HWT)) * HWT;
      transpose_fm<64>(pp.ctx + (size_t)b * 64 * HWs8,
                       pp.ws + OFF_TC + (size_t)b * HWs8 * 64, HWs8, hw0, tile);
    } else {
      tb -= TB_F1 + TB_F8 + TB_CTX;
      int b = tb / (HWs16 / HWT), hw0 = (tb % (HWs16 / HWT)) * HWT;
      transpose_fm<128>(pp.f16 + (size_t)b * 128 * HWs16,
                        pp.ws + OFF_T16 + (size_t)b * HWs16 * 128, HWs16, hw0, tile);
    }
  } else {
    // fused bias + pre-sigmoided gates
    int t = threadIdx.x;
    if (t < 128) {
      float acc = pp.bp[t];
      for (int j = 0; j < 128; ++j) acc = fmaf(pp.b2[j], pp.W[3][j * 128 + t], acc);
      ((float*)(pp.ws + OFF_BF))[t] = acc;
    } else {
      int i = t - 128;
      float a = pp.g1[i], b = pp.g2[i];
      ((float*)(pp.ws + OFF_G1S))[i] =
          __builtin_amdgcn_rcpf(1.0f + exp2_fast(a * -1.44269504f));
      ((float*)(pp.ws + OFF_G2S))[i] =
          __builtin_amdgcn_rcpf(1.0f + exp2_fast(b * -1.44269504f));
    }
  }
}

// ------------------------------ main kernel --------------------------------
struct Params {
  const float* coarse;
  const float* bc; const float* b1; const float* b3; const float* b4;
  const float* h0b; const float* h1b; const float* h2b;
  const float* h3w; const float* h3b;
  const unsigned short* ws;
  const unsigned short* wsT;   // feat1 T
  const unsigned short* wsT8;  // feat_s8 T
  const unsigned short* wsTC;  // ctx T
  const unsigned short* wsT16; // feat_s16 T
  const float* bF; const float* g1s; const float* g2s;  // f32 tables in ws
  float* out;
};

__device__ __forceinline__ void bilin_setup(float g, int Sg, int& i0, int& i1, float& w) {
  float s = (g + 1.0f) * (0.5f * Sg) - 0.5f;
  float f = floorf(s);
  w = s - f;
  int a = (int)f;
  i0 = min(max(a, 0), Sg - 1);
  i1 = min(max(a + 1, 0), Sg - 1);
}

template<int MTN, int NTN, int NKSN>
__device__ __forceinline__ void prefetchA(const unsigned short* __restrict__ Wsw,
                                          bf16x8* pf) {
  const int t = threadIdx.x;
  const int l = t & 63;
  const int wv = t >> 6;
  const int mt0 = (NTN == 2) ? wv * MTN : (wv >> 1);
  const unsigned short* ab = Wsw + (size_t)mt0 * NKSN * 512 + l * 8;
  if (MTN == 1) {
#pragma unroll
    for (int i = 0; i < 4; ++i) pf[i] = *(const bf16x8*)(ab + i * 512);
  } else {
    pf[0] = *(const bf16x8*)(ab);
    pf[1] = *(const bf16x8*)(ab + (size_t)NKSN * 512);
    pf[2] = *(const bf16x8*)(ab + 512);
    pf[3] = *(const bf16x8*)(ab + (size_t)NKSN * 512 + 512);
  }
}

// 32x32x16 MFMA layer; bias in accumulator init; first 4 A tiles from pf.
// EP: 0 none, 1 gelu, 2 relu, 3 gated+residual(LDS, pre-sig gate table),
//     5 gated+residual(in-register 4-tap gather from resT, pre-sig gate table)
template<int MT, int NT, int EP, bool SYNC, int K>
__device__ __forceinline__ void mfma_layer(
    const unsigned short* __restrict__ Wsw,
    const float* __restrict__ bias,
    const unsigned short* actIn,
    unsigned short* actOut,
    const float* __restrict__ gate,
    const unsigned short* res,
    const bf16x8* pf,
    const unsigned short* __restrict__ resT = nullptr,
    const int* ro0 = nullptr, const int* ro1 = nullptr,
    const float* rwx = nullptr, const float* rwy = nullptr)
{
  const int t = threadIdx.x;
  const int l = t & 63;
  const int wv = t >> 6;
  constexpr int nks = K >> 4;
  const int mt0 = (NT == 2) ? wv * MT : (wv >> 1);
  const int ntb = (NT == 2) ? 0 : (wv & 1);
  const int lh = l >> 5;
  const int ll = l & 31;

  f32x16 acc[MT][NT];
#pragma unroll
  for (int m = 0; m < MT; ++m) {
#pragma unroll
    for (int g = 0; g < 4; ++g) {
      const int f0 = (mt0 + m) * 32 + g * 8 + (lh << 2);
      const float4 bv = *(const float4*)(bias + f0);
#pragma unroll
      for (int nt = 0; nt < NT; ++nt) {
        acc[m][nt][g * 4 + 0] = bv.x; acc[m][nt][g * 4 + 1] = bv.y;
        acc[m][nt][g * 4 + 2] = bv.z; acc[m][nt][g * 4 + 3] = bv.w;
      }
    }
  }

  const unsigned short* bbase = actIn + (ntb * 32 + ll) * S + (lh << 3);
  const unsigned short* abase = Wsw + (size_t)mt0 * nks * 512 + l * 8;

  __builtin_amdgcn_s_setprio(1);
#pragma unroll
  for (int ks = 0; ks < nks; ++ks) {
    bf16x8 B[NT];
#pragma unroll
    for (int nt = 0; nt < NT; ++nt)
      B[nt] = *(const bf16x8*)(bbase + nt * 32 * S + ks * 16);
#pragma unroll
    for (int m = 0; m < MT; ++m) {
      bf16x8 A;
      if (ks * MT + m < 4) A = pf[ks * MT + m];
      else A = *(const bf16x8*)(abase + (m * nks + ks) * 512);
#pragma unroll
      for (int nt = 0; nt < NT; ++nt)
        acc[m][nt] = __builtin_amdgcn_mfma_f32_32x32x16_bf16(A, B[nt], acc[m][nt], 0, 0, 0);
    }
  }
  __builtin_amdgcn_s_setprio(0);

  if (SYNC) barrier_lds();

  // EP5: hoist per-nt residual tap geometry (from setup arrays in LDS)
  float rw00[NT], rw01[NT], rw10[NT], rw11[NT];
  int ro0v[NT], ro1v[NT], rduv[NT];
  if (EP == 5) {
#pragma unroll
    for (int nt = 0; nt < NT; ++nt) {
      const int pt = (ntb + nt) * 32 + ll;
      int e0 = ro0[pt], e1 = ro1[pt];
      float wx = rwx[pt], wy = rwy[pt];
      float w11 = wx * wy;
      rw11[nt] = w11; rw01[nt] = wx - w11; rw10[nt] = wy - w11;
      rw00[nt] = 1.0f - wx - wy + w11;
      rduv[nt] = (e0 & 1) * 128;
      ro0v[nt] = (e0 >> 1) * 128;
      ro1v[nt] = (e1 >> 1) * 128;
    }
  }

#pragma unroll
  for (int m = 0; m < MT; ++m) {
#pragma unroll
    for (int g = 0; g < 4; ++g) {
      const int f0 = (mt0 + m) * 32 + g * 8 + (lh << 2);
      float4 gv;
      if (EP == 3 || EP == 5) gv = *(const float4*)(gate + f0);  // pre-sigmoided
#pragma unroll
      for (int nt = 0; nt < NT; ++nt) {
        const int pt = (ntb + nt) * 32 + ll;
        float v[4];
        v[0] = acc[m][nt][g * 4 + 0]; v[1] = acc[m][nt][g * 4 + 1];
        v[2] = acc[m][nt][g * 4 + 2]; v[3] = acc[m][nt][g * 4 + 3];
        if (EP == 1) {
#pragma unroll
          for (int r = 0; r < 4; ++r) v[r] = gelu_fast(v[r]);
        } else if (EP == 2) {
#pragma unroll
          for (int r = 0; r < 4; ++r) v[r] = fmaxf(v[r], 0.0f);
        } else if (EP == 3) {
          uint2 rv = *(const uint2*)(res + pt * S + f0);
          v[0] = fmaf(gv.x, v[0], bflo(rv.x));
          v[1] = fmaf(gv.y, v[1], bfhi(rv.x));
          v[2] = fmaf(gv.z, v[2], bflo(rv.y));
          v[3] = fmaf(gv.w, v[3], bfhi(rv.y));
        } else if (EP == 5) {
          uint2 a00 = *(const uint2*)(resT + ro0v[nt] + f0);
          uint2 a01 = *(const uint2*)(resT + ro0v[nt] + rduv[nt] + f0);
          uint2 a10 = *(const uint2*)(resT + ro1v[nt] + f0);
          uint2 a11 = *(const uint2*)(resT + ro1v[nt] + rduv[nt] + f0);
          float r0 = rw00[nt] * bflo(a00.x) + rw01[nt] * bflo(a01.x)
                   + rw10[nt] * bflo(a10.x) + rw11[nt] * bflo(a11.x);
          float r1 = rw00[nt] * bfhi(a00.x) + rw01[nt] * bfhi(a01.x)
                   + rw10[nt] * bfhi(a10.x) + rw11[nt] * bfhi(a11.x);
          float r2 = rw00[nt] * bflo(a00.y) + rw01[nt] * bflo(a01.y)
                   + rw10[nt] * bflo(a10.y) + rw11[nt] * bflo(a11.y);
          float r3 = rw00[nt] * bfhi(a00.y) + rw01[nt] * bfhi(a01.y)
                   + rw10[nt] * bfhi(a10.y) + rw11[nt] * bfhi(a11.y);
          v[0] = fmaf(gv.x, v[0], r0);
          v[1] = fmaf(gv.y, v[1], r1);
          v[2] = fmaf(gv.z, v[2], r2);
          v[3] = fmaf(gv.w, v[3], r3);
        }
        uint2 pk;
        pk.x = pack2bf(v[0], v[1]);
        pk.y = pack2bf(v[2], v[3]);
        *(uint2*)(actOut + pt * S + f0) = pk;
      }
    }
  }
}

// 4-tap bilinear gather from transposed bf16 [HW][CH] map; 8 channels per item
template<int CH>
__device__ void gather_bilin(const unsigned short* __restrict__ T,
    const int* offA, const int* offB, const float* wxA, const float* wyA,
    unsigned short* outBuf, int colOff)
{
  constexpr int IPP = CH / 8;
  for (int it = threadIdx.x; it < MP * IPP; it += NTH) {
    int pt = it / IPP;
    int c8 = (it & (IPP - 1)) * 8;
    int e0 = offA[pt], e1 = offB[pt];
    int du = (e0 & 1) * CH;
    int o0 = (e0 >> 1) * CH + c8;
    int o1 = (e1 >> 1) * CH + c8;
    float wx = wxA[pt], wy = wyA[pt];
    uint4 a00 = *(const uint4*)(T + o0);
    uint4 a01 = *(const uint4*)(T + o0 + du);
    uint4 a10 = *(const uint4*)(T + o1);
    uint4 a11 = *(const uint4*)(T + o1 + du);
    float w11 = wx * wy;
    float w01 = wx - w11, w10 = wy - w11, w00 = 1.0f - wx - wy + w11;
    uint4 res;
    const unsigned* p00 = (const unsigned*)&a00;
    const unsigned* p01 = (const unsigned*)&a01;
    const unsigned* p10 = (const unsigned*)&a10;
    const unsigned* p11 = (const unsigned*)&a11;
    unsigned* pr = (unsigned*)&res;
#pragma unroll
    for (int q = 0; q < 4; ++q) {
      float r0 = w00 * bflo(p00[q]) + w01 * bflo(p01[q])
               + w10 * bflo(p10[q]) + w11 * bflo(p11[q]);
      float r1 = w00 * bfhi(p00[q]) + w01 * bfhi(p01[q])
               + w10 * bfhi(p10[q]) + w11 * bfhi(p11[q]);
      pr[q] = pack2bf(r0, r1);
    }
    *(uint4*)(outBuf + pt * S + colOff + c8) = res;
  }
}

__global__ __launch_bounds__(256, 4)
void ifd_kernel(Params p)
{
  __shared__ __align__(16) unsigned short buf[MP * S];   // 35840 B
  __shared__ int off8_0[MP], off8_1[MP];
  __shared__ int of16_0[MP], of16_1[MP];
  __shared__ int offT0[MP], offT1[MP];
  __shared__ float w8x[MP], w8y[MP], w16x[MP], w16y[MP], wWx[MP], wWy[MP];
  __shared__ float caxA[MP], cayA[MP];

  bf16x8 pf[4];

  const int blk = blockIdx.x;
  const int bb = blk / (HF * BPR);
  const int r = blk % (HF * BPR);
  const int y = r >> 3;
  const int xb = (r & (BPR - 1)) * MP;
  const int t = threadIdx.x;
  const float lim = 1.0f - 1e-6f;

  if (t < MP) {
    const int i = t;
    const int x = xb + i;
    float gx = (x + 0.5f) * (2.0f / WF_) - 1.0f;
    float gy = (y + 0.5f) * (2.0f / HF) - 1.0f;
    gx = fminf(fmaxf(gx, -lim), lim);
    gy = fminf(fmaxf(gy, -lim), lim);

    int x0, x1, y0, y1; float wx, wy;
    bilin_setup(gx, W8, x0, x1, wx);
    bilin_setup(gy, H8, y0, y1, wy);
    w8x[i] = wx; w8y[i] = wy;
    int du8 = x1 - x0;
    off8_0[i] = ((y0 * W8 + x0) << 1) | du8;
    off8_1[i] = ((y1 * W8 + x0) << 1) | du8;

    int a0, a1, b0i, b1i; float vx, vy;
    bilin_setup(gx, W16g, a0, a1, vx);
    bilin_setup(gy, H16g, b0i, b1i, vy);
    w16x[i] = vx; w16y[i] = vy;
    int du16 = a1 - a0;
    of16_0[i] = ((b0i * W16g + a0) << 1) | du16;
    of16_1[i] = ((b1i * W16g + a0) << 1) | du16;

    int o00 = y0 * W8 + x0, o01 = y0 * W8 + x1;
    int o10 = y1 * W8 + x0, o11 = y1 * W8 + x1;
    const float* cf = p.coarse + bb * 2 * HWs8;
    float c00 = cf[o00], c01 = cf[o01], c10 = cf[o10], c11 = cf[o11];
    float cx0 = fmaf(wx, c01 - c00, c00), cx1 = fmaf(wx, c11 - c10, c10);
    float cfx = fmaf(wy, cx1 - cx0, cx0);
    const float* cf2 = cf + HWs8;
    c00 = cf2[o00]; c01 = cf2[o01]; c10 = cf2[o10]; c11 = cf2[o11];
    cx0 = fmaf(wx, c01 - c00, c00); cx1 = fmaf(wx, c11 - c10, c10);
    float cfy = fmaf(wy, cx1 - cx0, cx0);
    float cax = cfx * 8.0f, cay = cfy * 8.0f;
    caxA[i] = cax; cayA[i] = cay;

    float wxn = gx + cax * (2.0f / WF_);
    float wyn = gy + cay * (2.0f / HF);
    wxn = fminf(fmaxf(wxn, -lim), lim);
    wyn = fminf(fmaxf(wyn, -lim), lim);
    int u0, u1, v0, v1; float uw, vw;
    bilin_setup(wxn, W8, u0, u1, uw);
    bilin_setup(wyn, H8, v0, v1, vw);
    int duW = u1 - u0;
    offT0[i] = ((v0 * W8 + u0) << 1) | duW;
    offT1[i] = ((v1 * W8 + u0) << 1) | duW;
    wWx[i] = uw; wWy[i] = vw;
  }
  prefetchA<1, 2, 4>(p.ws + OFF_WC, pf);
  barrier_lds();

  // gathers: f8 -> [128:256) (Wc residual), ctx -> [0:64) (Wc B)
  gather_bilin<128>(p.wsT8 + (size_t)bb * HWs8 * 128, off8_0, off8_1, w8x, w8y, buf, 128);
  gather_bilin<64>(p.wsTC + (size_t)bb * HWs8 * 64, off8_0, off8_1, w8x, w8y, buf, 0);
  barrier_lds();

  // Wc: [0:64) K=64 -> [128:256), res f8 (LDS), gate table g1s
  mfma_layer<1, 2, 3, false, 64>(p.ws + OFF_WC, p.bc, buf, buf + 128, p.g1s, buf + 128, pf);
  prefetchA<2, 2, 8>(p.ws + OFF_W1, pf);
  barrier_lds();
  // W1: [128:256) K=128 -> [0:256), gelu
  mfma_layer<2, 2, 1, true, 128>(p.ws + OFF_W1, p.b1, buf + 128, buf, nullptr, nullptr, pf);
  prefetchA<1, 2, 16>(p.ws + OFF_W2, pf);
  barrier_lds();
  // WF (fused W2@Wp): [0:256) K=256 -> [128:256), res f16 in-register, gate g2s
  mfma_layer<1, 2, 5, true, 256>(p.ws + OFF_W2, p.bF, buf, buf + 128, p.g2s, nullptr, pf,
                                 p.wsT16 + (size_t)bb * HWs16 * 128,
                                 of16_0, of16_1, w16x, w16y);
  prefetchA<2, 2, 8>(p.ws + OFF_W3, pf);
  barrier_lds();
  // W3: [128:256) K=128 -> [0:256), gelu
  mfma_layer<2, 2, 1, true, 128>(p.ws + OFF_W3, p.b3, buf + 128, buf, nullptr, nullptr, pf);
  prefetchA<1, 2, 16>(p.ws + OFF_W4, pf);
  barrier_lds();
  // W4: [0:256) K=256 -> [0:128); f1 gather -> [128:256); extras -> [256:272)
  mfma_layer<1, 2, 0, true, 256>(p.ws + OFF_W4, p.b4, buf, buf, nullptr, nullptr, pf);
  gather_bilin<128>(p.wsT + (size_t)bb * HWs8 * 128, offT0, offT1, wWx, wWy, buf, 128);
  for (int idx = t; idx < MP * 8; idx += NTH) {
    int row = idx >> 3, c = idx & 7;
    unsigned val = 0;
    if (c == 0) {
      float gx = fminf(fmaxf((xb + row + 0.5f) * (2.0f / WF_) - 1.0f, -lim), lim);
      float gy = fminf(fmaxf((y + 0.5f) * (2.0f / HF) - 1.0f, -lim), lim);
      val = pack2bf(gx, gy);
    } else if (c == 1) {
      val = pack2bf(caxA[row] * (1.0f / WF_), cayA[row] * (1.0f / HF));
    }
    *(unsigned*)(buf + row * S + 256 + c * 2) = val;
  }
  prefetchA<2, 2, 17>(p.ws + OFF_H0, pf);
  barrier_lds();
  // flow head, all in-place (H0 K padded 260 -> 272)
  mfma_layer<2, 2, 2, true, 272>(p.ws + OFF_H0, p.h0b, buf, buf, nullptr, nullptr, pf);
  prefetchA<1, 2, 16>(p.ws + OFF_H1, pf);
  barrier_lds();
  mfma_layer<1, 2, 2, true, 256>(p.ws + OFF_H1, p.h1b, buf, buf, nullptr, nullptr, pf);
  prefetchA<1, 1, 8>(p.ws + OFF_H2, pf);
  barrier_lds();
  mfma_layer<1, 1, 2, true, 128>(p.ws + OFF_H2, p.h2b, buf, buf, nullptr, nullptr, pf);
  barrier_lds();

  // final 64->2 + output (fp32)
  if (t < 128) {
    int i = t & 63, comp = t >> 6;
    float acc = p.h3b[comp];
    const unsigned short* rowp = buf + i * S;
    const float* wp = p.h3w + comp;
#pragma unroll
    for (int k8 = 0; k8 < 8; ++k8) {
      uint4 av = *(const uint4*)(rowp + k8 * 8);
      const float* w8p = wp + k8 * 16;
      acc = fmaf(bflo(av.x), w8p[0], acc);
      acc = fmaf(bfhi(av.x), w8p[2], acc);
      acc = fmaf(bflo(av.y), w8p[4], acc);
      acc = fmaf(bfhi(av.y), w8p[6], acc);
      acc = fmaf(bflo(av.z), w8p[8], acc);
      acc = fmaf(bfhi(av.z), w8p[10], acc);
      acc = fmaf(bflo(av.w), w8p[12], acc);
      acc = fmaf(bfhi(av.w), w8p[14], acc);
    }
    float flow = (comp ? cayA[i] : caxA[i]) + acc * (comp ? (float)HF : (float)WF_);
    p.out[((bb * 2 + comp) * HF + y) * WF_ + xb + i] = flow;
  }
}

extern "C" void kernel_launch(void* const* d_in, const int* in_sizes, int n_in,
                              void* d_out, int out_size, void* d_ws, size_t ws_size,
                              hipStream_t stream) {
  PrepParams pp;
  pp.W[0] = (const float*)d_in[6];   // Wc
  pp.W[1] = (const float*)d_in[9];   // W1
  pp.W[2] = (const float*)d_in[11];  // W2 (ffn1_w2) -> fused
  pp.W[3] = (const float*)d_in[13];  // Wp (proj_s8_w) -> fused
  pp.W[4] = (const float*)d_in[16];  // W3
  pp.W[5] = (const float*)d_in[18];  // W4
  pp.W[6] = (const float*)d_in[20];  // hw0
  pp.W[7] = (const float*)d_in[22];  // hw1
  pp.W[8] = (const float*)d_in[24];  // hw2
  pp.f1   = (const float*)d_in[2];
  pp.f8   = (const float*)d_in[1];
  pp.ctx  = (const float*)d_in[4];
  pp.f16  = (const float*)d_in[3];
  pp.b2   = (const float*)d_in[12];
  pp.bp   = (const float*)d_in[14];
  pp.g1   = (const float*)d_in[8];
  pp.g2   = (const float*)d_in[15];
  pp.ws = (unsigned short*)d_ws;
  hipLaunchKernelGGL(prep_kernel, dim3(PREP_W_BLOCKS + PREP_T_BLOCKS + 1), dim3(PTH),
                     0, stream, pp);

  Params p;
  p.coarse = (const float*)d_in[5];
  p.bc  = (const float*)d_in[7];
  p.b1  = (const float*)d_in[10];
  p.b3  = (const float*)d_in[17];
  p.b4  = (const float*)d_in[19];
  p.h0b = (const float*)d_in[21];
  p.h1b = (const float*)d_in[23];
  p.h2b = (const float*)d_in[25];
  p.h3w = (const float*)d_in[26];
  p.h3b = (const float*)d_in[27];
  p.ws   = (const unsigned short*)d_ws;
  p.wsT  = (const unsigned short*)d_ws + OFF_T;
  p.wsT8 = (const unsigned short*)d_ws + OFF_T8;
  p.wsTC = (const unsigned short*)d_ws + OFF_TC;
  p.wsT16= (const unsigned short*)d_ws + OFF_T16;
  p.bF   = (const float*)((const unsigned short*)d_ws + OFF_BF);
  p.g1s  = (const float*)((const unsigned short*)d_ws + OFF_G1S);
  p.g2s  = (const float*)((const unsigned short*)d_ws + OFF_G2S);
  p.out = (float*)d_out;

  hipLaunchKernelGGL(ifd_kernel, dim3(NBLK), dim3(NTH), 0, stream, p);
}

// Round 6
// 387.859 us; speedup vs baseline: 1.1887x; 1.0341x over previous
//
#include <hip/hip_runtime.h>
#include <math.h>

// ---------------------------------------------------------------------------
// ImplicitFlowDecoder — R14b (identical to R14; prior round was an infra
// failure — container never came up; kernel re-audited: uniform barriers,
// no races on buf dead-cols, prefetch index order verified, VGPR < 128):
//  - deeper A-prefetch: pf[8] for MT=1 layers (WF/W4/H1 half-covered, H2 fully
//    A-free); MT=2 layers keep pf[4] (acc-register pressure).
//  - parallel setup: geometry computed by all 256 threads; coarse-flow taps
//    split across the 4 thread-groups (partials in buf dead cols [64:80));
//    combine + warp offsets + extras moved after barrier 1 (overlaps gathers).
//  - extras written as 2x uint4 per point (loop removed from W4 slot).
// R13: W2@Wp fused (one layer deleted); f16 residual in-register (EP5);
//      pre-sigmoided gates. R12: all maps [HW][C] bf16 + uint4 gathers.
// R11: lgkm-only barriers. R10: constexpr prep, H0 K=272, exp2 gelu, setprio.
// ---------------------------------------------------------------------------

typedef short bf16x8 __attribute__((ext_vector_type(8)));
typedef float f32x16 __attribute__((ext_vector_type(16)));

constexpr int W8 = 64, H8 = 48, W16g = 32, H16g = 24, WF_ = 512, HF = 384;
constexpr int HWs8 = W8 * H8;      // 3072
constexpr int HWs16 = W16g * H16g; // 768
constexpr int MP = 64;
constexpr int NTH = 256;
constexpr int BPR = WF_ / MP;               // 8
constexpr int NBLK = 2 * HF * BPR;          // 6144

constexpr int S = 280;      // row stride (ushorts), 8-aligned for b128

// d_ws layout (ushort elems)
constexpr int OFF_WC = 0;
constexpr int OFF_W1 = 8192;
constexpr int OFF_W2 = 40960;    // fused WF (256x128)
constexpr int OFF_WP = 73728;    // unused region (layout stability)
constexpr int OFF_W3 = 90112;
constexpr int OFF_W4 = 122880;
constexpr int OFF_H0 = 155648;   // K padded 260->272
constexpr int OFF_H1 = 225280;
constexpr int OFF_H2 = 258048;
constexpr int SWZ_TOTAL = 266240;
// transposed feature maps, bf16 [B][HW][C]
constexpr int OFF_T   = SWZ_TOTAL;                 // feat1   [2][3072][128]
constexpr int OFF_T8  = OFF_T  + 2 * HWs8 * 128;   // feat_s8 [2][3072][128]
constexpr int OFF_TC  = OFF_T8 + 2 * HWs8 * 128;   // ctx     [2][3072][64]
constexpr int OFF_T16 = OFF_TC + 2 * HWs8 * 64;    // feat_s16[2][768][128]
// small f32 tables
constexpr int OFF_BF  = OFF_T16 + 2 * HWs16 * 128;
constexpr int OFF_G1S = OFF_BF + 256;
constexpr int OFF_G2S = OFF_G1S + 256;

__device__ __forceinline__ unsigned short f2bf(float f) {  // RNE (prep only)
  union { float f; unsigned u; } v; v.f = f;
  unsigned r = (v.u + 0x7fffu + ((v.u >> 16) & 1u)) >> 16;
  return (unsigned short)r;
}
__device__ __forceinline__ float bflo(unsigned u) {
  return __builtin_bit_cast(float, u << 16);
}
__device__ __forceinline__ float bfhi(unsigned u) {
  return __builtin_bit_cast(float, u & 0xffff0000u);
}
#if defined(__has_builtin)
#if __has_builtin(__builtin_amdgcn_cvt_pk_bf16_f32)
#define HAS_PK_BF16 1
#endif
#if __has_builtin(__builtin_amdgcn_exp2f)
#define HAS_EXP2 1
#endif
#endif
__device__ __forceinline__ unsigned pack2bf(float a, float b) {
#ifdef HAS_PK_BF16
  typedef __bf16 bf2_t __attribute__((ext_vector_type(2)));
  bf2_t r = __builtin_amdgcn_cvt_pk_bf16_f32(a, b);
  return __builtin_bit_cast(unsigned, r);
#else
  unsigned ua = __builtin_bit_cast(unsigned, a) + 0x8000u;
  unsigned ub = __builtin_bit_cast(unsigned, b) + 0x8000u;
  return __builtin_amdgcn_perm(ub, ua, 0x07060302u);
#endif
}
__device__ __forceinline__ float exp2_fast(float x) {
#ifdef HAS_EXP2
  return __builtin_amdgcn_exp2f(x);
#else
  float r;
  asm("v_exp_f32 %0, %1" : "=v"(r) : "v"(x));
  return r;
#endif
}
// tanh-GELU in sigmoid form with log2e pre-folded
__device__ __forceinline__ float gelu_fast(float x) {
  float t = fmaf(x * x, -0.10294433f, -2.3022082f);
  float e = exp2_fast(x * t);
  return x * __builtin_amdgcn_rcpf(1.0f + e);
}

// LDS-only barrier: no vmcnt(0) drain (no cross-thread global deps in-kernel).
__device__ __forceinline__ void barrier_lds() {
  asm volatile("s_waitcnt lgkmcnt(0)" ::: "memory");
  __builtin_amdgcn_s_barrier();
  asm volatile("" ::: "memory");
}

// ------------------------------- prep kernel -------------------------------
struct PrepParams {
  const float* W[9];
  const float* f1; const float* f8; const float* ctx; const float* f16;
  const float* b2; const float* bp; const float* g1; const float* g2;
  unsigned short* ws;
};

constexpr int PTH = 256;
constexpr int PREP_W_BLOCKS = SWZ_TOTAL / PTH;   // 1040
constexpr int HWT = 32;
constexpr int TB_F1 = 2 * (HWs8 / HWT);
constexpr int TB_F8 = TB_F1;
constexpr int TB_CTX = TB_F1;
constexpr int TB_F16 = 2 * (HWs16 / HWT);
constexpr int PREP_T_BLOCKS = TB_F1 + TB_F8 + TB_CTX + TB_F16;  // 624

template<int KK, int KP, int NN>
__device__ __forceinline__ void prep_one(const float* __restrict__ W,
                                         unsigned short* __restrict__ dst, int q) {
  int j = q & 7;
  int l = (q >> 3) & 63;
  int r = q >> 9;
  constexpr int nks = KP >> 4;
  int ks = r % nks;
  int mt = r / nks;
  int n = mt * 32 + (l & 31);
  int k = ks * 16 + ((l >> 5) << 3) + j;
  float v = (k < KK) ? W[k * NN + n] : 0.0f;
  dst[q] = f2bf(v);
}

// fused WF[k][n] = sum_j W2[k][j] * Wp[j][n]   (K=256, N=128), fp32 accumulate
__device__ __forceinline__ void prep_fused(const float* __restrict__ W2,
                                           const float* __restrict__ Wp,
                                           unsigned short* __restrict__ dst, int q) {
  int j = q & 7;
  int l = (q >> 3) & 63;
  int r = q >> 9;
  constexpr int nks = 16;
  int ks = r % nks;
  int mt = r / nks;
  int n = mt * 32 + (l & 31);
  int k = ks * 16 + ((l >> 5) << 3) + j;
  float v = 0.0f;
  for (int jj = 0; jj < 128; ++jj)
    v = fmaf(W2[k * 128 + jj], Wp[jj * 128 + n], v);
  dst[q] = f2bf(v);
}

template<int C>
__device__ __forceinline__ void transpose_fm(const float* __restrict__ src,
    unsigned short* __restrict__ dst, int HWtot, int hw0,
    unsigned short* __restrict__ tile)
{
  const int t = threadIdx.x;
  const int hw = t & (HWT - 1);
  const int cg = t >> 5;
#pragma unroll
  for (int c0 = 0; c0 < C / 8; ++c0) {
    int c = c0 * 8 + cg;
    tile[c * (HWT + 2) + hw] = f2bf(src[(size_t)c * HWtot + hw0 + hw]);
  }
  __syncthreads();
  constexpr int CD = C / 2;
  constexpr int RP = 256 / CD;
  const int cD = t & (CD - 1);
  const int hg = t / CD;
#pragma unroll
  for (int h0 = 0; h0 < HWT / RP; ++h0) {
    int hh = h0 * RP + hg;
    unsigned lo = tile[(2 * cD) * (HWT + 2) + hh];
    unsigned hi = tile[(2 * cD + 1) * (HWT + 2) + hh];
    *(unsigned*)(dst + (size_t)(hw0 + hh) * C + 2 * cD) = lo | (hi << 16);
  }
}

__global__ void prep_kernel(PrepParams pp) {
  __shared__ unsigned short tile[128 * (HWT + 2)];
  const int blk = blockIdx.x;
  if (blk < PREP_W_BLOCKS) {
    int e = blk * PTH + threadIdx.x;
    unsigned short* ws = pp.ws;
    if (e < OFF_W1)      prep_one<64, 64, 128>(pp.W[0], ws + OFF_WC, e - OFF_WC);
    else if (e < OFF_W2) prep_one<128, 128, 256>(pp.W[1], ws + OFF_W1, e - OFF_W1);
    else if (e < OFF_WP) prep_fused(pp.W[2], pp.W[3], ws + OFF_W2, e - OFF_W2);
    else if (e < OFF_W3) { /* unused */ }
    else if (e < OFF_W4) prep_one<128, 128, 256>(pp.W[4], ws + OFF_W3, e - OFF_W3);
    else if (e < OFF_H0) prep_one<256, 256, 128>(pp.W[5], ws + OFF_W4, e - OFF_W4);
    else if (e < OFF_H1) prep_one<260, 272, 256>(pp.W[6], ws + OFF_H0, e - OFF_H0);
    else if (e < OFF_H2) prep_one<256, 256, 128>(pp.W[7], ws + OFF_H1, e - OFF_H1);
    else                 prep_one<128, 128, 64>(pp.W[8], ws + OFF_H2, e - OFF_H2);
  } else if (blk < PREP_W_BLOCKS + PREP_T_BLOCKS) {
    int tb = blk - PREP_W_BLOCKS;
    if (tb < TB_F1) {
      int b = tb / (HWs8 / HWT), hw0 = (tb % (HWs8 / HWT)) * HWT;
      transpose_fm<128>(pp.f1 + (size_t)b * 128 * HWs8,
                        pp.ws + OFF_T + (size_t)b * HWs8 * 128, HWs8, hw0, tile);
    } else if (tb < TB_F1 + TB_F8) {
      tb -= TB_F1;
      int b = tb / (HWs8 / HWT), hw0 = (tb % (HWs8 / HWT)) * HWT;
      transpose_fm<128>(pp.f8 + (size_t)b * 128 * HWs8,
                        pp.ws + OFF_T8 + (size_t)b * HWs8 * 128, HWs8, hw0, tile);
    } else if (tb < TB_F1 + TB_F8 + TB_CTX) {
      tb -= TB_F1 + TB_F8;
      int b = tb / (HWs8 / HWT), hw0 = (tb % (HWs8 / HWT)) * HWT;
      transpose_fm<64>(pp.ctx + (size_t)b * 64 * HWs8,
                       pp.ws + OFF_TC + (size_t)b * HWs8 * 64, HWs8, hw0, tile);
    } else {
      tb -= TB_F1 + TB_F8 + TB_CTX;
      int b = tb / (HWs16 / HWT), hw0 = (tb % (HWs16 / HWT)) * HWT;
      transpose_fm<128>(pp.f16 + (size_t)b * 128 * HWs16,
                        pp.ws + OFF_T16 + (size_t)b * HWs16 * 128, HWs16, hw0, tile);
    }
  } else {
    int t = threadIdx.x;
    if (t < 128) {
      float acc = pp.bp[t];
      for (int j = 0; j < 128; ++j) acc = fmaf(pp.b2[j], pp.W[3][j * 128 + t], acc);
      ((float*)(pp.ws + OFF_BF))[t] = acc;
    } else {
      int i = t - 128;
      float a = pp.g1[i], b = pp.g2[i];
      ((float*)(pp.ws + OFF_G1S))[i] =
          __builtin_amdgcn_rcpf(1.0f + exp2_fast(a * -1.44269504f));
      ((float*)(pp.ws + OFF_G2S))[i] =
          __builtin_amdgcn_rcpf(1.0f + exp2_fast(b * -1.44269504f));
    }
  }
}

// ------------------------------ main kernel --------------------------------
struct Params {
  const float* coarse;
  const float* bc; const float* b1; const float* b3; const float* b4;
  const float* h0b; const float* h1b; const float* h2b;
  const float* h3w; const float* h3b;
  const unsigned short* ws;
  const unsigned short* wsT;   // feat1 T
  const unsigned short* wsT8;  // feat_s8 T
  const unsigned short* wsTC;  // ctx T
  const unsigned short* wsT16; // feat_s16 T
  const float* bF; const float* g1s; const float* g2s;
  float* out;
};

__device__ __forceinline__ void bilin_setup(float g, int Sg, int& i0, int& i1, float& w) {
  float s = (g + 1.0f) * (0.5f * Sg) - 0.5f;
  float f = floorf(s);
  w = s - f;
  int a = (int)f;
  i0 = min(max(a, 0), Sg - 1);
  i1 = min(max(a + 1, 0), Sg - 1);
}

// prefetch the next layer's first D A-tiles (consumption order: ks-major, m-minor)
template<int MTN, int NTN, int NKSN, int D>
__device__ __forceinline__ void prefetchA(const unsigned short* __restrict__ Wsw,
                                          bf16x8* pf) {
  const int t = threadIdx.x;
  const int l = t & 63;
  const int wv = t >> 6;
  const int mt0 = (NTN == 2) ? wv * MTN : (wv >> 1);
  const unsigned short* ab = Wsw + (size_t)mt0 * NKSN * 512 + l * 8;
#pragma unroll
  for (int idx = 0; idx < D; ++idx) {
    const int ks = (MTN == 2) ? (idx >> 1) : idx;
    const int m  = (MTN == 2) ? (idx & 1) : 0;
    pf[idx] = *(const bf16x8*)(ab + ((size_t)m * NKSN + ks) * 512);
  }
}

// 32x32x16 MFMA layer; bias in accumulator init; first PD A tiles from pf.
// EP: 0 none, 1 gelu, 2 relu, 3 gated+residual(LDS), 5 gated+residual(in-reg)
template<int MT, int NT, int EP, bool SYNC, int K, int PD>
__device__ __forceinline__ void mfma_layer(
    const unsigned short* __restrict__ Wsw,
    const float* __restrict__ bias,
    const unsigned short* actIn,
    unsigned short* actOut,
    const float* __restrict__ gate,
    const unsigned short* res,
    const bf16x8* pf,
    const unsigned short* __restrict__ resT = nullptr,
    const int* ro0 = nullptr, const int* ro1 = nullptr,
    const float* rwx = nullptr, const float* rwy = nullptr)
{
  const int t = threadIdx.x;
  const int l = t & 63;
  const int wv = t >> 6;
  constexpr int nks = K >> 4;
  const int mt0 = (NT == 2) ? wv * MT : (wv >> 1);
  const int ntb = (NT == 2) ? 0 : (wv & 1);
  const int lh = l >> 5;
  const int ll = l & 31;

  f32x16 acc[MT][NT];
#pragma unroll
  for (int m = 0; m < MT; ++m) {
#pragma unroll
    for (int g = 0; g < 4; ++g) {
      const int f0 = (mt0 + m) * 32 + g * 8 + (lh << 2);
      const float4 bv = *(const float4*)(bias + f0);
#pragma unroll
      for (int nt = 0; nt < NT; ++nt) {
        acc[m][nt][g * 4 + 0] = bv.x; acc[m][nt][g * 4 + 1] = bv.y;
        acc[m][nt][g * 4 + 2] = bv.z; acc[m][nt][g * 4 + 3] = bv.w;
      }
    }
  }

  const unsigned short* bbase = actIn + (ntb * 32 + ll) * S + (lh << 3);
  const unsigned short* abase = Wsw + (size_t)mt0 * nks * 512 + l * 8;

  __builtin_amdgcn_s_setprio(1);
#pragma unroll
  for (int ks = 0; ks < nks; ++ks) {
    bf16x8 B[NT];
#pragma unroll
    for (int nt = 0; nt < NT; ++nt)
      B[nt] = *(const bf16x8*)(bbase + nt * 32 * S + ks * 16);
#pragma unroll
    for (int m = 0; m < MT; ++m) {
      bf16x8 A;
      if (ks * MT + m < PD) A = pf[ks * MT + m];
      else A = *(const bf16x8*)(abase + (m * nks + ks) * 512);
#pragma unroll
      for (int nt = 0; nt < NT; ++nt)
        acc[m][nt] = __builtin_amdgcn_mfma_f32_32x32x16_bf16(A, B[nt], acc[m][nt], 0, 0, 0);
    }
  }
  __builtin_amdgcn_s_setprio(0);

  if (SYNC) barrier_lds();

  // EP5: hoist per-nt residual tap geometry
  float rw00[NT], rw01[NT], rw10[NT], rw11[NT];
  int ro0v[NT], ro1v[NT], rduv[NT];
  if (EP == 5) {
#pragma unroll
    for (int nt = 0; nt < NT; ++nt) {
      const int pt = (ntb + nt) * 32 + ll;
      int e0 = ro0[pt], e1 = ro1[pt];
      float wx = rwx[pt], wy = rwy[pt];
      float w11 = wx * wy;
      rw11[nt] = w11; rw01[nt] = wx - w11; rw10[nt] = wy - w11;
      rw00[nt] = 1.0f - wx - wy + w11;
      rduv[nt] = (e0 & 1) * 128;
      ro0v[nt] = (e0 >> 1) * 128;
      ro1v[nt] = (e1 >> 1) * 128;
    }
  }

#pragma unroll
  for (int m = 0; m < MT; ++m) {
#pragma unroll
    for (int g = 0; g < 4; ++g) {
      const int f0 = (mt0 + m) * 32 + g * 8 + (lh << 2);
      float4 gv;
      if (EP == 3 || EP == 5) gv = *(const float4*)(gate + f0);  // pre-sigmoided
#pragma unroll
      for (int nt = 0; nt < NT; ++nt) {
        const int pt = (ntb + nt) * 32 + ll;
        float v[4];
        v[0] = acc[m][nt][g * 4 + 0]; v[1] = acc[m][nt][g * 4 + 1];
        v[2] = acc[m][nt][g * 4 + 2]; v[3] = acc[m][nt][g * 4 + 3];
        if (EP == 1) {
#pragma unroll
          for (int r = 0; r < 4; ++r) v[r] = gelu_fast(v[r]);
        } else if (EP == 2) {
#pragma unroll
          for (int r = 0; r < 4; ++r) v[r] = fmaxf(v[r], 0.0f);
        } else if (EP == 3) {
          uint2 rv = *(const uint2*)(res + pt * S + f0);
          v[0] = fmaf(gv.x, v[0], bflo(rv.x));
          v[1] = fmaf(gv.y, v[1], bfhi(rv.x));
          v[2] = fmaf(gv.z, v[2], bflo(rv.y));
          v[3] = fmaf(gv.w, v[3], bfhi(rv.y));
        } else if (EP == 5) {
          uint2 a00 = *(const uint2*)(resT + ro0v[nt] + f0);
          uint2 a01 = *(const uint2*)(resT + ro0v[nt] + rduv[nt] + f0);
          uint2 a10 = *(const uint2*)(resT + ro1v[nt] + f0);
          uint2 a11 = *(const uint2*)(resT + ro1v[nt] + rduv[nt] + f0);
          float r0 = rw00[nt] * bflo(a00.x) + rw01[nt] * bflo(a01.x)
                   + rw10[nt] * bflo(a10.x) + rw11[nt] * bflo(a11.x);
          float r1 = rw00[nt] * bfhi(a00.x) + rw01[nt] * bfhi(a01.x)
                   + rw10[nt] * bfhi(a10.x) + rw11[nt] * bfhi(a11.x);
          float r2 = rw00[nt] * bflo(a00.y) + rw01[nt] * bflo(a01.y)
                   + rw10[nt] * bflo(a10.y) + rw11[nt] * bflo(a11.y);
          float r3 = rw00[nt] * bfhi(a00.y) + rw01[nt] * bfhi(a01.y)
                   + rw10[nt] * bfhi(a10.y) + rw11[nt] * bfhi(a11.y);
          v[0] = fmaf(gv.x, v[0], r0);
          v[1] = fmaf(gv.y, v[1], r1);
          v[2] = fmaf(gv.z, v[2], r2);
          v[3] = fmaf(gv.w, v[3], r3);
        }
        uint2 pk;
        pk.x = pack2bf(v[0], v[1]);
        pk.y = pack2bf(v[2], v[3]);
        *(uint2*)(actOut + pt * S + f0) = pk;
      }
    }
  }
}

// 4-tap bilinear gather from transposed bf16 [HW][CH] map; 8 channels per item
template<int CH>
__device__ void gather_bilin(const unsigned short* __restrict__ T,
    const int* offA, const int* offB, const float* wxA, const float* wyA,
    unsigned short* outBuf, int colOff)
{
  constexpr int IPP = CH / 8;
  for (int it = threadIdx.x; it < MP * IPP; it += NTH) {
    int pt = it / IPP;
    int c8 = (it & (IPP - 1)) * 8;
    int e0 = offA[pt], e1 = offB[pt];
    int du = (e0 & 1) * CH;
    int o0 = (e0 >> 1) * CH + c8;
    int o1 = (e1 >> 1) * CH + c8;
    float wx = wxA[pt], wy = wyA[pt];
    uint4 a00 = *(const uint4*)(T + o0);
    uint4 a01 = *(const uint4*)(T + o0 + du);
    uint4 a10 = *(const uint4*)(T + o1);
    uint4 a11 = *(const uint4*)(T + o1 + du);
    float w11 = wx * wy;
    float w01 = wx - w11, w10 = wy - w11, w00 = 1.0f - wx - wy + w11;
    uint4 res;
    const unsigned* p00 = (const unsigned*)&a00;
    const unsigned* p01 = (const unsigned*)&a01;
    const unsigned* p10 = (const unsigned*)&a10;
    const unsigned* p11 = (const unsigned*)&a11;
    unsigned* pr = (unsigned*)&res;
#pragma unroll
    for (int q = 0; q < 4; ++q) {
      float r0 = w00 * bflo(p00[q]) + w01 * bflo(p01[q])
               + w10 * bflo(p10[q]) + w11 * bflo(p11[q]);
      float r1 = w00 * bfhi(p00[q]) + w01 * bfhi(p01[q])
               + w10 * bfhi(p10[q]) + w11 * bfhi(p11[q]);
      pr[q] = pack2bf(r0, r1);
    }
    *(uint4*)(outBuf + pt * S + colOff + c8) = res;
  }
}

__global__ __launch_bounds__(256, 4)
void ifd_kernel(Params p)
{
  __shared__ __align__(16) unsigned short buf[MP * S];   // 35840 B
  __shared__ int off8_0[MP], off8_1[MP];
  __shared__ int of16_0[MP], of16_1[MP];
  __shared__ int offT0[MP], offT1[MP];
  __shared__ float w8x[MP], w8y[MP], w16x[MP], w16y[MP], wWx[MP], wWy[MP];
  __shared__ float caxA[MP], cayA[MP];

  bf16x8 pf[8];

  const int blk = blockIdx.x;
  const int bb = blk / (HF * BPR);
  const int r = blk % (HF * BPR);
  const int y = r >> 3;
  const int xb = (r & (BPR - 1)) * MP;
  const int t = threadIdx.x;
  const int i = t & 63;          // point
  const int tg = t >> 6;         // tap group
  const float lim = 1.0f - 1e-6f;

  // ---- phase A (all 256 threads): geometry + one coarse-flow tap each ----
  {
    const int x = xb + i;
    float gx = (x + 0.5f) * (2.0f / WF_) - 1.0f;
    float gy = (y + 0.5f) * (2.0f / HF) - 1.0f;
    gx = fminf(fmaxf(gx, -lim), lim);
    gy = fminf(fmaxf(gy, -lim), lim);

    int x0, x1, y0, y1; float wx, wy;
    bilin_setup(gx, W8, x0, x1, wx);
    bilin_setup(gy, H8, y0, y1, wy);
    if (tg == 0) {
      w8x[i] = wx; w8y[i] = wy;
      int du8 = x1 - x0;
      off8_0[i] = ((y0 * W8 + x0) << 1) | du8;
      off8_1[i] = ((y1 * W8 + x0) << 1) | du8;
      int a0, a1, b0i, b1i; float vx, vy;
      bilin_setup(gx, W16g, a0, a1, vx);
      bilin_setup(gy, H16g, b0i, b1i, vy);
      w16x[i] = vx; w16y[i] = vy;
      int du16 = a1 - a0;
      of16_0[i] = ((b0i * W16g + a0) << 1) | du16;
      of16_1[i] = ((b1i * W16g + a0) << 1) | du16;
    }
    // this group's tap: tg = (ty<<1)|tx
    int xt = (tg & 1) ? x1 : x0;
    int yt = (tg >> 1) ? y1 : y0;
    float wt = ((tg & 1) ? wx : 1.0f - wx) * ((tg >> 1) ? wy : 1.0f - wy);
    const float* cf = p.coarse + bb * 2 * HWs8;
    int o = yt * W8 + xt;
    float px = wt * cf[o];
    float py = wt * cf[HWs8 + o];
    // partials in buf dead cols [64:80) (f32 view): 8 floats per point row
    float* fp = (float*)(buf + i * S + 64);
    fp[tg * 2 + 0] = px;
    fp[tg * 2 + 1] = py;
  }
  prefetchA<1, 2, 4, 4>(p.ws + OFF_WC, pf);
  barrier_lds();

  // ---- phase B: t<64 combine taps + warp offsets + extras (overlaps gathers)
  if (t < MP) {
    const float* fp = (const float*)(buf + i * S + 64);
    float cfx = (fp[0] + fp[2]) + (fp[4] + fp[6]);
    float cfy = (fp[1] + fp[3]) + (fp[5] + fp[7]);
    float cax = cfx * 8.0f, cay = cfy * 8.0f;
    caxA[i] = cax; cayA[i] = cay;

    const int x = xb + i;
    float gx = fminf(fmaxf((x + 0.5f) * (2.0f / WF_) - 1.0f, -lim), lim);
    float gy = fminf(fmaxf((y + 0.5f) * (2.0f / HF) - 1.0f, -lim), lim);
    float wxn = fminf(fmaxf(gx + cax * (2.0f / WF_), -lim), lim);
    float wyn = fminf(fmaxf(gy + cay * (2.0f / HF), -lim), lim);
    int u0, u1, v0, v1; float uw, vw;
    bilin_setup(wxn, W8, u0, u1, uw);
    bilin_setup(wyn, H8, v0, v1, vw);
    int duW = u1 - u0;
    offT0[i] = ((v0 * W8 + u0) << 1) | duW;
    offT1[i] = ((v1 * W8 + u0) << 1) | duW;
    wWx[i] = uw; wWy[i] = vw;

    // extras cols [256:272): gx,gy | cnx,cny | zeros
    uint4 e0; e0.x = pack2bf(gx, gy);
    e0.y = pack2bf(cax * (1.0f / WF_), cay * (1.0f / HF));
    e0.z = 0; e0.w = 0;
    *(uint4*)(buf + i * S + 256) = e0;
    uint4 ez; ez.x = 0; ez.y = 0; ez.z = 0; ez.w = 0;
    *(uint4*)(buf + i * S + 264) = ez;
  }

  // gathers: f8 -> [128:256) (Wc residual), ctx -> [0:64) (Wc B)
  gather_bilin<128>(p.wsT8 + (size_t)bb * HWs8 * 128, off8_0, off8_1, w8x, w8y, buf, 128);
  gather_bilin<64>(p.wsTC + (size_t)bb * HWs8 * 64, off8_0, off8_1, w8x, w8y, buf, 0);
  barrier_lds();

  // Wc: [0:64) K=64 -> [128:256), res f8 (LDS), gate table g1s
  mfma_layer<1, 2, 3, false, 64, 4>(p.ws + OFF_WC, p.bc, buf, buf + 128, p.g1s, buf + 128, pf);
  prefetchA<2, 2, 8, 4>(p.ws + OFF_W1, pf);
  barrier_lds();
  // W1: [128:256) K=128 -> [0:256), gelu
  mfma_layer<2, 2, 1, true, 128, 4>(p.ws + OFF_W1, p.b1, buf + 128, buf, nullptr, nullptr, pf);
  prefetchA<1, 2, 16, 8>(p.ws + OFF_W2, pf);
  barrier_lds();
  // WF (fused W2@Wp): [0:256) K=256 -> [128:256), res f16 in-register, gate g2s
  mfma_layer<1, 2, 5, true, 256, 8>(p.ws + OFF_W2, p.bF, buf, buf + 128, p.g2s, nullptr, pf,
                                    p.wsT16 + (size_t)bb * HWs16 * 128,
                                    of16_0, of16_1, w16x, w16y);
  prefetchA<2, 2, 8, 4>(p.ws + OFF_W3, pf);
  barrier_lds();
  // W3: [128:256) K=128 -> [0:256), gelu
  mfma_layer<2, 2, 1, true, 128, 4>(p.ws + OFF_W3, p.b3, buf + 128, buf, nullptr, nullptr, pf);
  prefetchA<1, 2, 16, 8>(p.ws + OFF_W4, pf);
  barrier_lds();
  // W4: [0:256) K=256 -> [0:128); f1 gather -> [128:256)
  mfma_layer<1, 2, 0, true, 256, 8>(p.ws + OFF_W4, p.b4, buf, buf, nullptr, nullptr, pf);
  gather_bilin<128>(p.wsT + (size_t)bb * HWs8 * 128, offT0, offT1, wWx, wWy, buf, 128);
  prefetchA<2, 2, 17, 4>(p.ws + OFF_H0, pf);
  barrier_lds();
  // flow head, all in-place (H0 K padded 260 -> 272)
  mfma_layer<2, 2, 2, true, 272, 4>(p.ws + OFF_H0, p.h0b, buf, buf, nullptr, nullptr, pf);
  prefetchA<1, 2, 16, 8>(p.ws + OFF_H1, pf);
  barrier_lds();
  mfma_layer<1, 2, 2, true, 256, 8>(p.ws + OFF_H1, p.h1b, buf, buf, nullptr, nullptr, pf);
  prefetchA<1, 1, 8, 8>(p.ws + OFF_H2, pf);
  barrier_lds();
  mfma_layer<1, 1, 2, true, 128, 8>(p.ws + OFF_H2, p.h2b, buf, buf, nullptr, nullptr, pf);
  barrier_lds();

  // final 64->2 + output (fp32)
  if (t < 128) {
    int ii = t & 63, comp = t >> 6;
    float acc = p.h3b[comp];
    const unsigned short* rowp = buf + ii * S;
    const float* wp = p.h3w + comp;
#pragma unroll
    for (int k8 = 0; k8 < 8; ++k8) {
      uint4 av = *(const uint4*)(rowp + k8 * 8);
      const float* w8p = wp + k8 * 16;
      acc = fmaf(bflo(av.x), w8p[0], acc);
      acc = fmaf(bfhi(av.x), w8p[2], acc);
      acc = fmaf(bflo(av.y), w8p[4], acc);
      acc = fmaf(bfhi(av.y), w8p[6], acc);
      acc = fmaf(bflo(av.z), w8p[8], acc);
      acc = fmaf(bfhi(av.z), w8p[10], acc);
      acc = fmaf(bflo(av.w), w8p[12], acc);
      acc = fmaf(bfhi(av.w), w8p[14], acc);
    }
    float flow = (comp ? cayA[ii] : caxA[ii]) + acc * (comp ? (float)HF : (float)WF_);
    p.out[((bb * 2 + comp) * HF + y) * WF_ + xb + ii] = flow;
  }
}

extern "C" void kernel_launch(void* const* d_in, const int* in_sizes, int n_in,
                              void* d_out, int out_size, void* d_ws, size_t ws_size,
                              hipStream_t stream) {
  PrepParams pp;
  pp.W[0] = (const float*)d_in[6];   // Wc
  pp.W[1] = (const float*)d_in[9];   // W1
  pp.W[2] = (const float*)d_in[11];  // W2 (ffn1_w2) -> fused
  pp.W[3] = (const float*)d_in[13];  // Wp (proj_s8_w) -> fused
  pp.W[4] = (const float*)d_in[16];  // W3
  pp.W[5] = (const float*)d_in[18];  // W4
  pp.W[6] = (const float*)d_in[20];  // hw0
  pp.W[7] = (const float*)d_in[22];  // hw1
  pp.W[8] = (const float*)d_in[24];  // hw2
  pp.f1   = (const float*)d_in[2];
  pp.f8   = (const float*)d_in[1];
  pp.ctx  = (const float*)d_in[4];
  pp.f16  = (const float*)d_in[3];
  pp.b2   = (const float*)d_in[12];
  pp.bp   = (const float*)d_in[14];
  pp.g1   = (const float*)d_in[8];
  pp.g2   = (const float*)d_in[15];
  pp.ws = (unsigned short*)d_ws;
  hipLaunchKernelGGL(prep_kernel, dim3(PREP_W_BLOCKS + PREP_T_BLOCKS + 1), dim3(PTH),
                     0, stream, pp);

  Params p;
  p.coarse = (const float*)d_in[5];
  p.bc  = (const float*)d_in[7];
  p.b1  = (const float*)d_in[10];
  p.b3  = (const float*)d_in[17];
  p.b4  = (const float*)d_in[19];
  p.h0b = (const float*)d_in[21];
  p.h1b = (const float*)d_in[23];
  p.h2b = (const float*)d_in[25];
  p.h3w = (const float*)d_in[26];
  p.h3b = (const float*)d_in[27];
  p.ws   = (const unsigned short*)d_ws;
  p.wsT  = (const unsigned short*)d_ws + OFF_T;
  p.wsT8 = (const unsigned short*)d_ws + OFF_T8;
  p.wsTC = (const unsigned short*)d_ws + OFF_TC;
  p.wsT16= (const unsigned short*)d_ws + OFF_T16;
  p.bF   = (const float*)((const unsigned short*)d_ws + OFF_BF);
  p.g1s  = (const float*)((const unsigned short*)d_ws + OFF_G1S);
  p.g2s  = (const float*)((const unsigned short*)d_ws + OFF_G2S);
  p.out = (float*)d_out;

  hipLaunchKernelGGL(ifd_kernel, dim3(NBLK), dim3(NTH), 0, stream, p);
}